// Round 1
// 2768.606 us; speedup vs baseline: 1.0436x; 1.0436x over previous
//
#include <hip/hip_runtime.h>
#include <math.h>

#define TT   2048
#define DD   1024
#define HH   16
#define HSS  64
#define EE   8
#define KTOP 2
#define LL   2
#define CAPP 512
#define NN   2048
#define DFF  4096
#define NK   (NN*KTOP)
#define HALF 32

typedef __attribute__((ext_vector_type(8))) short bf16x8;
typedef __attribute__((ext_vector_type(4))) float f32x4;

// split fp32 v into 3 bf16 planes (RNE bit-math; v = s0 + s1 + s2 to ~2^-27 rel)
__device__ __forceinline__ void split3(float v, short& s0, short& s1, short& s2) {
  union { float f; unsigned u; } a, b0, c, b1, d;
  a.f = v;
  unsigned t0 = (a.u + 0x7fffu + ((a.u >> 16) & 1u)) & 0xffff0000u;
  b0.u = t0;
  float r1 = v - b0.f;
  c.f = r1;
  unsigned t1 = (c.u + 0x7fffu + ((c.u >> 16) & 1u)) & 0xffff0000u;
  b1.u = t1;
  float r2 = r1 - b1.f;
  d.f = r2;
  unsigned t2 = d.u + 0x7fffu + ((d.u >> 16) & 1u);
  s0 = (short)(t0 >> 16); s1 = (short)(t1 >> 16); s2 = (short)(t2 >> 16);
}

// async global->LDS 16B (dest = wave-uniform LDS base + lane*16)
__device__ __forceinline__ void gld16(const short* g, short* l) {
  __builtin_amdgcn_global_load_lds(
      (const __attribute__((address_space(1))) unsigned int*)g,
      (__attribute__((address_space(3))) unsigned int*)l, 16, 0, 0);
}

// ---------------- embedding ----------------
__global__ __launch_bounds__(256) void embed_kernel(const int* __restrict__ ids,
                                                    const float* __restrict__ tok,
                                                    const float* __restrict__ pos,
                                                    float* __restrict__ x) {
  int t = blockIdx.x, tid = threadIdx.x;
  int id = ids[t];
  float4 a = ((const float4*)(tok + (long long)id * DD))[tid];
  float4 b = ((const float4*)(pos + (long long)t * DD))[tid];
  float4 r;
  r.x = a.x + b.x; r.y = a.y + b.y; r.z = a.z + b.z; r.w = a.w + b.w;
  ((float4*)(x + (long long)t * DD))[tid] = r;
}

// ---------------- RoPE sin/cos table ----------------
__global__ __launch_bounds__(256) void sincos_kernel(float* __restrict__ st, float* __restrict__ ct) {
  int idx = blockIdx.x * 256 + threadIdx.x;
  int t = idx >> 5, i = idx & 31;
  double div = exp(-(double)(2 * i) * (9.210340371976184 / 64.0));
  double a = (double)t * div;
  st[idx] = (float)sin(a);
  ct[idx] = (float)cos(a);
}

// ---------------- fp32 -> 3 bf16 plane conversion (8 elems/thread) ----------------
__global__ __launch_bounds__(256) void convert_kernel(const float* __restrict__ in,
                                                      short* __restrict__ out, long long n) {
  long long i = ((long long)blockIdx.x * 256 + threadIdx.x) * 8;
  float4 v0 = *(const float4*)(in + i);
  float4 v1 = *(const float4*)(in + i + 4);
  float vv[8] = {v0.x, v0.y, v0.z, v0.w, v1.x, v1.y, v1.z, v1.w};
  short s0[8], s1[8], s2[8];
#pragma unroll
  for (int j = 0; j < 8; j++) split3(vv[j], s0[j], s1[j], s2[j]);
  *(short4*)(out + i)         = make_short4(s0[0], s0[1], s0[2], s0[3]);
  *(short4*)(out + i + 4)     = make_short4(s0[4], s0[5], s0[6], s0[7]);
  *(short4*)(out + n + i)     = make_short4(s1[0], s1[1], s1[2], s1[3]);
  *(short4*)(out + n + i + 4) = make_short4(s1[4], s1[5], s1[6], s1[7]);
  *(short4*)(out + 2*n + i)   = make_short4(s2[0], s2[1], s2[2], s2[3]);
  *(short4*)(out + 2*n + i+4) = make_short4(s2[4], s2[5], s2[6], s2[7]);
}

// ---------------- layernorm (+ optional bf16x3 plane output) ----------------
__global__ __launch_bounds__(256) void ln_kernel(const float* __restrict__ in, float* __restrict__ out,
                                                 short* __restrict__ yp,
                                                 const float* __restrict__ w, const float* __restrict__ b) {
  int row = blockIdx.x, tid = threadIdx.x;
  float4 v = ((const float4*)(in + (long long)row * DD))[tid];
  float s = v.x + v.y + v.z + v.w;
  float q = v.x * v.x + v.y * v.y + v.z * v.z + v.w * v.w;
#pragma unroll
  for (int off = 32; off > 0; off >>= 1) {
    s += __shfl_down(s, off);
    q += __shfl_down(q, off);
  }
  __shared__ float rs[4], rq[4];
  int wv = tid >> 6;
  if ((tid & 63) == 0) { rs[wv] = s; rq[wv] = q; }
  __syncthreads();
  float S = rs[0] + rs[1] + rs[2] + rs[3];
  float Q = rq[0] + rq[1] + rq[2] + rq[3];
  float mean = S * (1.0f / DD);
  float var = Q * (1.0f / DD) - mean * mean;
  float rstd = rsqrtf(var + 1e-5f);
  float4 wv4 = ((const float4*)w)[tid];
  float4 bv4 = ((const float4*)b)[tid];
  float4 r;
  r.x = (v.x - mean) * rstd * wv4.x + bv4.x;
  r.y = (v.y - mean) * rstd * wv4.y + bv4.y;
  r.z = (v.z - mean) * rstd * wv4.z + bv4.z;
  r.w = (v.w - mean) * rstd * wv4.w + bv4.w;
  ((float4*)(out + (long long)row * DD))[tid] = r;
  if (yp) {
    float rr[4] = {r.x, r.y, r.z, r.w};
    short a0[4], a1[4], a2[4];
#pragma unroll
    for (int j = 0; j < 4; j++) split3(rr[j], a0[j], a1[j], a2[j]);
    size_t off = (size_t)row * DD + tid * 4;
    *(short4*)(yp + off)                    = make_short4(a0[0], a0[1], a0[2], a0[3]);
    *(short4*)(yp + (size_t)NN*DD + off)    = make_short4(a1[0], a1[1], a1[2], a1[3]);
    *(short4*)(yp + (size_t)2*NN*DD + off)  = make_short4(a2[0], a2[1], a2[2], a2[3]);
  }
}

// ---------------- fp32 tiled GEMM (fallback path) ----------------
__global__ __launch_bounds__(256) void gemm_kernel(
    const float* __restrict__ Aall, const float* __restrict__ Ball,
    const float* __restrict__ biasAll, const float* __restrict__ resAll,
    float* __restrict__ Call, int M, int Nn, int Kd, int flags,
    long long sA, long long sB, long long sBias, long long sC) {
  const float* A = Aall + (long long)blockIdx.z * sA;
  const float* B = Ball + (long long)blockIdx.z * sB;
  float* C = Call + (long long)blockIdx.z * sC;
  __shared__ float As[128 * 17];
  __shared__ float Bs[128 * 17];
  int tid = threadIdx.x;
  int tx = tid & 15, ty = tid >> 4;
  int bm = blockIdx.y * 128, bn = blockIdx.x * 128;
  int lrow = tid >> 2;
  int lk = (tid & 3) << 2;
  float acc[8][8];
#pragma unroll
  for (int i = 0; i < 8; i++)
#pragma unroll
    for (int j = 0; j < 8; j++) acc[i][j] = 0.f;
  const float* Arow0 = A + (long long)(bm + lrow) * Kd + lk;
  const float* Arow1 = A + (long long)(bm + lrow + 64) * Kd + lk;
  const float* Brow0 = B + (long long)(bn + lrow) * Kd + lk;
  const float* Brow1 = B + (long long)(bn + lrow + 64) * Kd + lk;
  for (int kb = 0; kb < Kd; kb += 16) {
    float4 a0 = *(const float4*)(Arow0 + kb);
    float4 a1 = *(const float4*)(Arow1 + kb);
    float4 b0 = *(const float4*)(Brow0 + kb);
    float4 b1 = *(const float4*)(Brow1 + kb);
    __syncthreads();
    As[lrow * 17 + lk + 0] = a0.x; As[lrow * 17 + lk + 1] = a0.y;
    As[lrow * 17 + lk + 2] = a0.z; As[lrow * 17 + lk + 3] = a0.w;
    As[(lrow + 64) * 17 + lk + 0] = a1.x; As[(lrow + 64) * 17 + lk + 1] = a1.y;
    As[(lrow + 64) * 17 + lk + 2] = a1.z; As[(lrow + 64) * 17 + lk + 3] = a1.w;
    Bs[lrow * 17 + lk + 0] = b0.x; Bs[lrow * 17 + lk + 1] = b0.y;
    Bs[lrow * 17 + lk + 2] = b0.z; Bs[lrow * 17 + lk + 3] = b0.w;
    Bs[(lrow + 64) * 17 + lk + 0] = b1.x; Bs[(lrow + 64) * 17 + lk + 1] = b1.y;
    Bs[(lrow + 64) * 17 + lk + 2] = b1.z; Bs[(lrow + 64) * 17 + lk + 3] = b1.w;
    __syncthreads();
#pragma unroll
    for (int k = 0; k < 16; k++) {
      float av[8], bv[8];
#pragma unroll
      for (int i = 0; i < 8; i++) av[i] = As[(ty + 16 * i) * 17 + k];
#pragma unroll
      for (int j = 0; j < 8; j++) bv[j] = Bs[(tx + 16 * j) * 17 + k];
#pragma unroll
      for (int i = 0; i < 8; i++)
#pragma unroll
        for (int j = 0; j < 8; j++) acc[i][j] = fmaf(av[i], bv[j], acc[i][j]);
    }
  }
  const float* bias = (flags & 1) ? (biasAll + (long long)blockIdx.z * sBias) : nullptr;
  const float* res = (flags & 4) ? (resAll + (long long)blockIdx.z * sC) : nullptr;
#pragma unroll
  for (int i = 0; i < 8; i++) {
    int row = bm + ty + 16 * i;
#pragma unroll
    for (int j = 0; j < 8; j++) {
      int col = bn + tx + 16 * j;
      float v = acc[i][j];
      if (flags & 1) v += bias[col];
      if (flags & 2) v = fmaxf(v, 0.f);
      if (flags & 4) v += res[(long long)row * Nn + col];
      C[(long long)row * Nn + col] = v;
    }
  }
}

// ---------------- bf16x3 emulated-fp32 MFMA GEMM (m97 structure) ----------------
// C = A(MxK) * B(NxK)^T from pre-split bf16 planes (Ap/Bp: [3][batch][rows][K]).
// flags: 1=bias, 2=relu, 4=residual(fp32 C only), 8=fast(3 products), 16=C as bf16x3 planes.
// 128x128 tile, 256 thr = 4 waves (2x2 of 64x64), 16x16x32 bf16 MFMA.
// Staging: global_load_lds dwordx4 into linear [3][128][32] shorts (48 KB, 3 blocks/CU),
// chunk-swizzled on the GLOBAL source (c ^ ((row>>1)&3)) so swizzled reads are 2-way-free.
// XCD-aware bijective block swizzle (all grids divisible by 8).
__global__ __launch_bounds__(256, 3) void gemm_mfma(
    const short* __restrict__ Ap, const short* __restrict__ Bp,
    const float* __restrict__ biasAll, const float* __restrict__ resAll,
    void* __restrict__ Call, int M, int Nn, int Kd, int flags,
    long long sA, long long sB, long long sBias, long long sC,
    long long PA, long long PB, long long PC) {
  const bool fast = (flags & 8);
  const int np = fast ? 2 : 3;
  __shared__ short As[3][128][32];
  __shared__ short Bs[3][128][32];
  int tid = threadIdx.x;

  // ---- XCD-aware swizzle of flattened block index ----
  int gx = gridDim.x, gy = gridDim.y;
  int nwg = gx * gy * gridDim.z;          // always divisible by 8 here
  int flat = blockIdx.x + gx * (blockIdx.y + gy * blockIdx.z);
  int cpx = nwg >> 3;
  int wkid = (flat & 7) * cpx + (flat >> 3);
  int bz = wkid / (gx * gy);
  int rem = wkid - bz * gx * gy;
  int by = rem / gx, bx = rem - by * gx;

  int bm = by * 128, bn = bx * 128;
  long long zA = (long long)bz * sA;
  long long zB = (long long)bz * sB;

  int wid = tid >> 6, lane = tid & 63;
  int lrow = lane >> 2, lchunk = lane & 3;
  // stored chunk = linear chunk ^ ((row>>1)&3); row = h*64 + wid*16 + lrow,
  // and (row>>1)&3 == (lrow>>1)&3 (h*64, wid*16 are multiples of 16).
  int cs = lchunk ^ ((lrow >> 1) & 3);
  const short* gAbase = Ap + zA + (long long)(bm + wid * 16 + lrow) * Kd + cs * 8;
  const short* gBbase = Bp + zB + (long long)(bn + wid * 16 + lrow) * Kd + cs * 8;
  long long hstepA = (long long)64 * Kd;  // +64 rows

  int wm = (wid & 1) * 64, wn = (wid >> 1) * 64;
  int tr = lane & 15, quad = lane >> 4;
  int qsw = (quad ^ ((tr >> 1) & 3)) << 3;  // swizzled read offset (shorts)

  f32x4 acc[4][4];
#pragma unroll
  for (int i = 0; i < 4; i++)
#pragma unroll
    for (int j = 0; j < 4; j++) acc[i][j] = (f32x4){0.f, 0.f, 0.f, 0.f};

  for (int kb = 0; kb < Kd; kb += 32) {
    __syncthreads();
#pragma unroll
    for (int p = 0; p < 3; p++) {
      if (p < np) {
#pragma unroll
        for (int h = 0; h < 2; h++) {
          int rb = h * 64 + wid * 16;
          gld16(gAbase + p * PA + h * hstepA + kb, &As[p][rb][0]);
          gld16(gBbase + p * PB + h * hstepA + kb, &Bs[p][rb][0]);
        }
      }
    }
    __syncthreads();   // compiler drains vmcnt(0) here: LDS tile ready
    bf16x8 af[4][3];
#pragma unroll
    for (int mi = 0; mi < 4; mi++) {
      int ar = wm + mi * 16 + tr;
      af[mi][0] = *(const bf16x8*)&As[0][ar][qsw];
      af[mi][1] = *(const bf16x8*)&As[1][ar][qsw];
      af[mi][2] = fast ? af[mi][0] : *(const bf16x8*)&As[2][ar][qsw];
    }
#pragma unroll
    for (int nj = 0; nj < 4; nj++) {
      int br = wn + nj * 16 + tr;
      bf16x8 b0 = *(const bf16x8*)&Bs[0][br][qsw];
      bf16x8 b1 = *(const bf16x8*)&Bs[1][br][qsw];
      bf16x8 b2 = fast ? b0 : *(const bf16x8*)&Bs[2][br][qsw];
#pragma unroll
      for (int mi = 0; mi < 4; mi++) {
        f32x4 c = acc[mi][nj];
        c = __builtin_amdgcn_mfma_f32_16x16x32_bf16(af[mi][1], b0, c, 0, 0, 0); // a1b0
        c = __builtin_amdgcn_mfma_f32_16x16x32_bf16(af[mi][0], b1, c, 0, 0, 0); // a0b1
        if (!fast) {
          c = __builtin_amdgcn_mfma_f32_16x16x32_bf16(af[mi][2], b0, c, 0, 0, 0); // a2b0
          c = __builtin_amdgcn_mfma_f32_16x16x32_bf16(af[mi][1], b1, c, 0, 0, 0); // a1b1
          c = __builtin_amdgcn_mfma_f32_16x16x32_bf16(af[mi][0], b2, c, 0, 0, 0); // a0b2
        }
        c = __builtin_amdgcn_mfma_f32_16x16x32_bf16(af[mi][0], b0, c, 0, 0, 0);   // a0b0
        acc[mi][nj] = c;
      }
    }
  }

  long long z = bz;
  const float* bias = (flags & 1) ? (biasAll + z * sBias) : nullptr;
  if (flags & 16) {
    short* Cs = (short*)Call;
#pragma unroll
    for (int mi = 0; mi < 4; mi++)
#pragma unroll
      for (int nj = 0; nj < 4; nj++) {
        int col = bn + wn + nj * 16 + tr;
#pragma unroll
        for (int rg = 0; rg < 4; rg++) {
          int row = bm + wm + mi * 16 + quad * 4 + rg;
          float v = acc[mi][nj][rg];
          if (flags & 1) v += bias[col];
          if (flags & 2) v = fmaxf(v, 0.f);
          short s0, s1, s2;
          split3(v, s0, s1, s2);
          long long off = z * sC + (long long)row * Nn + col;
          Cs[off] = s0; Cs[PC + off] = s1; Cs[2 * PC + off] = s2;
        }
      }
  } else {
    float* C = (float*)Call;
    const float* res = (flags & 4) ? (resAll + z * sC) : nullptr;
#pragma unroll
    for (int mi = 0; mi < 4; mi++)
#pragma unroll
      for (int nj = 0; nj < 4; nj++) {
        int col = bn + wn + nj * 16 + tr;
#pragma unroll
        for (int rg = 0; rg < 4; rg++) {
          int row = bm + wm + mi * 16 + quad * 4 + rg;
          float v = acc[mi][nj][rg];
          if (flags & 1) v += bias[col];
          if (flags & 2) v = fmaxf(v, 0.f);
          if (flags & 4) v += res[(long long)row * Nn + col];
          C[z * sC + (long long)row * Nn + col] = v;
        }
      }
  }
  (void)M;
}

// ---------------- RoPE in place ----------------
__global__ __launch_bounds__(256) void rope_kernel(float* __restrict__ qkv,
                                                   const float* __restrict__ st,
                                                   const float* __restrict__ ct) {
  int t = blockIdx.x, tid = threadIdx.x;
#pragma unroll
  for (int p = tid; p < HH * HALF; p += 256) {
    int h = p >> 5, i = p & 31;
    float s = st[t * HALF + i], c = ct[t * HALF + i];
    float* q = qkv + (long long)t * (3 * DD) + h * HSS;
    float q1 = q[i], q2 = q[i + HALF];
    q[i] = q1 * c - q2 * s;
    q[i + HALF] = q2 * c + q1 * s;
    float* k = q + DD;
    float k1 = k[i], k2 = k[i + HALF];
    k[i] = k1 * c - k2 * s;
    k[i + HALF] = k2 * c + k1 * s;
  }
}

// ---------------- flash attention: key-split across 4 waves ----------------
__global__ __launch_bounds__(256, 1) void attn_kernel(const float* __restrict__ qkv,
                                                      float* __restrict__ attn,
                                                      short* __restrict__ ap) {
  int bid = blockIdx.x;
  int head = bid & 15;
  int qc = (bid < 256) ? (31 - (bid >> 4)) : ((bid - 256) >> 4);
  int tid = threadIdx.x;
  int w = tid >> 6;
  int r = tid & 63;
  int qrow = qc * 64 + r;
  int nkt = qc + 1;

  __shared__ float4 KVbuf[4][2][16][16];
  __shared__ float Ms[4][64];
  __shared__ float Ls[4][64];

  float4 q[16], o[16];
  const float4* qp = (const float4*)(qkv + (long long)qrow * (3 * DD) + head * HSS);
#pragma unroll
  for (int d = 0; d < 16; d++) { q[d] = qp[d]; o[d] = make_float4(0.f, 0.f, 0.f, 0.f); }
  float m = -INFINITY, l = 0.f;

  for (int kt = w; kt < nkt; kt += 4) {
    bool diag = (kt == qc);
#pragma unroll 1
    for (int s = 0; s < 4; s++) {
      int kbase = kt * 64 + s * 16;
#pragma unroll
      for (int it = 0; it < 4; it++) {
        int fid = r + it * 64;
        int krow = fid >> 4, d4 = fid & 15;
        const float* bK = qkv + (long long)(kbase + krow) * (3 * DD) + DD + head * HSS + d4 * 4;
        KVbuf[w][0][krow][d4] = *(const float4*)bK;
        KVbuf[w][1][krow][d4] = *(const float4*)(bK + DD);
      }
      float sbuf[16];
#pragma unroll
      for (int jj = 0; jj < 16; jj++) {
        const float4* kr = KVbuf[w][0][jj];
        float sv = 0.f;
#pragma unroll
        for (int d = 0; d < 16; d++) {
          float4 kv = kr[d];
          sv = fmaf(q[d].x, kv.x, sv); sv = fmaf(q[d].y, kv.y, sv);
          sv = fmaf(q[d].z, kv.z, sv); sv = fmaf(q[d].w, kv.w, sv);
        }
        sv *= 0.125f;
        if (diag && (kbase + jj > qrow)) sv = -1e30f;
        sbuf[jj] = sv;
      }
      float gm = m;
#pragma unroll
      for (int jj = 0; jj < 16; jj++) gm = fmaxf(gm, sbuf[jj]);
      float scale = __expf(m - gm);
      m = gm;
      l *= scale;
#pragma unroll
      for (int d = 0; d < 16; d++) {
        o[d].x *= scale; o[d].y *= scale; o[d].z *= scale; o[d].w *= scale;
      }
#pragma unroll
      for (int jj = 0; jj < 16; jj++) {
        float p = __expf(sbuf[jj] - m);
        l += p;
        const float4* vr = KVbuf[w][1][jj];
#pragma unroll
        for (int d = 0; d < 16; d++) {
          float4 vv = vr[d];
          o[d].x = fmaf(p, vv.x, o[d].x); o[d].y = fmaf(p, vv.y, o[d].y);
          o[d].z = fmaf(p, vv.z, o[d].z); o[d].w = fmaf(p, vv.w, o[d].w);
        }
      }
    }
  }

  typedef float4 OscRow[64][5];
  OscRow* Osc = reinterpret_cast<OscRow*>(&KVbuf[0][0][0][0]);
  int rr = tid & 63, ii = tid >> 6;
  long long obase = (long long)head * TT * HSS + (long long)(qc * 64 + rr) * HSS;
#pragma unroll
  for (int c = 0; c < 4; c++) {
    __syncthreads();
    Osc[w][r][0] = o[c * 4 + 0];
    Osc[w][r][1] = o[c * 4 + 1];
    Osc[w][r][2] = o[c * 4 + 2];
    Osc[w][r][3] = o[c * 4 + 3];
    if (c == 0) { Ms[w][r] = m; Ls[w][r] = l; }
    __syncthreads();
    float m0 = Ms[0][rr], m1 = Ms[1][rr], m2 = Ms[2][rr], m3 = Ms[3][rr];
    float M = fmaxf(fmaxf(m0, m1), fmaxf(m2, m3));
    float s0 = __expf(m0 - M), s1 = __expf(m1 - M);
    float s2 = __expf(m2 - M), s3 = __expf(m3 - M);
    float L = s0 * Ls[0][rr] + s1 * Ls[1][rr] + s2 * Ls[2][rr] + s3 * Ls[3][rr];
    float rl = 1.f / L;
    float4 a0 = Osc[0][rr][ii], a1 = Osc[1][rr][ii];
    float4 a2 = Osc[2][rr][ii], a3 = Osc[3][rr][ii];
    float4 res;
    res.x = (s0 * a0.x + s1 * a1.x + s2 * a2.x + s3 * a3.x) * rl;
    res.y = (s0 * a0.y + s1 * a1.y + s2 * a2.y + s3 * a3.y) * rl;
    res.z = (s0 * a0.z + s1 * a1.z + s2 * a2.z + s3 * a3.z) * rl;
    res.w = (s0 * a0.w + s1 * a1.w + s2 * a2.w + s3 * a3.w) * rl;
    long long oaddr = obase + c * 16 + ii * 4;
    *(float4*)(attn + oaddr) = res;
    if (ap) {
      float rv[4] = {res.x, res.y, res.z, res.w};
      short p0[4], p1[4], p2[4];
#pragma unroll
      for (int j = 0; j < 4; j++) split3(rv[j], p0[j], p1[j], p2[j]);
      *(short4*)(ap + oaddr)                    = make_short4(p0[0], p0[1], p0[2], p0[3]);
      *(short4*)(ap + (size_t)NN*DD + oaddr)    = make_short4(p1[0], p1[1], p1[2], p1[3]);
      *(short4*)(ap + (size_t)2*NN*DD + oaddr)  = make_short4(p2[0], p2[1], p2[2], p2[3]);
    }
  }
}

// ---------------- router ----------------
__global__ __launch_bounds__(64) void router_kernel(
    const float* __restrict__ y, const float* __restrict__ rw, const float* __restrict__ rb,
    const float* __restrict__ nw, const float* __restrict__ nb, const float* __restrict__ noise,
    int* __restrict__ slot_e, float* __restrict__ slot_g) {
  int n = blockIdx.x;
  int lane = threadIdx.x;
  double accr[EE], accn[EE];
#pragma unroll
  for (int e = 0; e < EE; e++) { accr[e] = 0.0; accn[e] = 0.0; }
  for (int j = 0; j < 16; j++) {
    float xv = y[(long long)n * DD + j * 64 + lane];
#pragma unroll
    for (int e = 0; e < EE; e++) {
      accr[e] += (double)xv * (double)rw[e * DD + j * 64 + lane];
      accn[e] += (double)xv * (double)nw[e * DD + j * 64 + lane];
    }
  }
#pragma unroll
  for (int e = 0; e < EE; e++) {
    for (int off = 32; off > 0; off >>= 1) {
      accr[e] += __shfl_down(accr[e], off);
      accn[e] += __shfl_down(accn[e], off);
    }
  }
  if (lane == 0) {
    float noisy[EE];
#pragma unroll
    for (int e = 0; e < EE; e++) {
      float lg = (float)accr[e] + rb[e];
      float nl = (float)accn[e] + nb[e];
      float sp = (nl > 0.f) ? (nl + log1pf(expf(-nl))) : log1pf(expf(nl));
      noisy[e] = lg + noise[n * EE + e] * sp;
    }
    int i0 = 0;
#pragma unroll
    for (int e = 1; e < EE; e++) if (noisy[e] > noisy[i0]) i0 = e;
    int i1 = -1;
#pragma unroll
    for (int e = 0; e < EE; e++) {
      if (e == i0) continue;
      if (i1 < 0 || noisy[e] > noisy[i1]) i1 = e;
    }
    float v0 = noisy[i0], v1 = noisy[i1];
    float e1 = __expf(v1 - v0);
    float inv = 1.f / (1.f + e1);
    slot_e[2 * n] = i0; slot_e[2 * n + 1] = i1;
    slot_g[2 * n] = inv; slot_g[2 * n + 1] = e1 * inv;
  }
}

// ---------------- deterministic rank scan ----------------
__global__ __launch_bounds__(256) void scan_kernel(const int* __restrict__ slot_e,
                                                   int* __restrict__ slot_pos) {
  __shared__ int cnt[256 * EE];
  int tid = threadIdx.x;
  int base = tid * 16;
  int c[EE];
#pragma unroll
  for (int e = 0; e < EE; e++) c[e] = 0;
  int loc[16];
  for (int i = 0; i < 16; i++) {
    int e = slot_e[base + i];
    loc[i] = e;
    c[e]++;
  }
#pragma unroll
  for (int e = 0; e < EE; e++) cnt[tid * EE + e] = c[e];
  __syncthreads();
  if (tid < EE) {
    int run = 0;
    for (int t2 = 0; t2 < 256; t2++) {
      int v = cnt[t2 * EE + tid];
      cnt[t2 * EE + tid] = run;
      run += v;
    }
  }
  __syncthreads();
  int run[EE];
#pragma unroll
  for (int e = 0; e < EE; e++) run[e] = cnt[tid * EE + e];
  for (int i = 0; i < 16; i++) {
    int e = loc[i];
    int r = run[e]++;
    slot_pos[base + i] = (r < CAPP) ? (e * CAPP + r) : -1;
  }
}

// ---------------- dispatch (fp32 fallback) ----------------
__global__ __launch_bounds__(256) void dispatch_kernel(const float* __restrict__ y,
                                                       const int* __restrict__ slot_pos,
                                                       float* __restrict__ disp) {
  int i = blockIdx.x;
  int pos = slot_pos[i];
  if (pos < 0) return;
  int tok = i >> 1;
  ((float4*)(disp + (long long)pos * DD))[threadIdx.x] =
      ((const float4*)(y + (long long)tok * DD))[threadIdx.x];
}

// ---------------- dispatch (bf16x3 planes) ----------------
__global__ __launch_bounds__(256) void dispatch_planes_kernel(const short* __restrict__ yp,
                                                              const int* __restrict__ slot_pos,
                                                              short* __restrict__ dp) {
  int i = blockIdx.x;
  int pos = slot_pos[i];
  if (pos < 0) return;
  int tok = i >> 1;
#pragma unroll
  for (int p = 0; p < 3; p++) {
    short4 v = ((const short4*)(yp + (size_t)p * NN * DD + (size_t)tok * DD))[threadIdx.x];
    ((short4*)(dp + (size_t)p * EE * CAPP * DD + (size_t)pos * DD))[threadIdx.x] = v;
  }
}

// ---------------- combine ----------------
__global__ __launch_bounds__(256) void combine_kernel(float* __restrict__ x,
                                                      const float* __restrict__ eo,
                                                      const int* __restrict__ slot_pos,
                                                      const float* __restrict__ slot_g) {
  int n = blockIdx.x, tid = threadIdx.x;
  int p0 = slot_pos[2 * n], p1 = slot_pos[2 * n + 1];
  float g0 = slot_g[2 * n], g1 = slot_g[2 * n + 1];
  float4 v = ((float4*)(x + (long long)n * DD))[tid];
  if (p0 >= 0) {
    float4 e0 = ((const float4*)(eo + (long long)p0 * DD))[tid];
    v.x = fmaf(g0, e0.x, v.x); v.y = fmaf(g0, e0.y, v.y);
    v.z = fmaf(g0, e0.z, v.z); v.w = fmaf(g0, e0.w, v.w);
  }
  if (p1 >= 0) {
    float4 e1 = ((const float4*)(eo + (long long)p1 * DD))[tid];
    v.x = fmaf(g1, e1.x, v.x); v.y = fmaf(g1, e1.y, v.y);
    v.z = fmaf(g1, e1.z, v.z); v.w = fmaf(g1, e1.w, v.w);
  }
  ((float4*)(x + (long long)n * DD))[tid] = v;
}

extern "C" void kernel_launch(void* const* d_in, const int* in_sizes, int n_in,
                              void* d_out, int out_size, void* d_ws, size_t ws_size,
                              hipStream_t stream) {
  const int* input_ids = (const int*)d_in[0];
  const float* noise = (const float*)d_in[1];
  const float* tok_emb = (const float*)d_in[2];
  const float* pos_emb = (const float*)d_in[3];
  const float* ln1_w = (const float*)d_in[4];
  const float* ln1_b = (const float*)d_in[5];
  const float* ln2_w = (const float*)d_in[6];
  const float* ln2_b = (const float*)d_in[7];
  const float* qkv_w = (const float*)d_in[8];
  const float* out_w = (const float*)d_in[9];
  const float* router_w = (const float*)d_in[10];
  const float* router_b = (const float*)d_in[11];
  const float* noise_w = (const float*)d_in[12];
  const float* noise_b = (const float*)d_in[13];
  const float* e_w1 = (const float*)d_in[14];
  const float* e_b1 = (const float*)d_in[15];
  const float* e_w2 = (const float*)d_in[16];
  const float* e_b2 = (const float*)d_in[17];
  const float* lnf_w = (const float*)d_in[18];
  const float* lnf_b = (const float*)d_in[19];
  float* out = (float*)d_out;

  // ---- workspace layout ----
  float* ws = (float*)d_ws;
  size_t off = 0;
  float* x = ws + off;       off += (size_t)NN * DD;
  float* y = ws + off;       off += (size_t)NN * DD;
  float* qkv = ws + off;     off += (size_t)NN * 3 * DD;
  float* eo = ws + off;      off += (size_t)EE * CAPP * DD;
  float* sintab = ws + off;  off += (size_t)TT * HALF;
  float* costab = ws + off;  off += (size_t)TT * HALF;
  float* attn32 = ws + off;  off += (size_t)NN * DD;
  int* slot_e = (int*)(ws + off);   off += NK;
  int* slot_pos = (int*)(ws + off); off += NK;
  float* slot_g = ws + off;  off += NK;
  size_t base_floats = off;
  float* disp32 = ws + off;
  float* hbuf32 = disp32 + (size_t)EE * CAPP * DD;
  size_t fb_need = (base_floats + (size_t)EE * CAPP * DD + (size_t)EE * CAPP * DFF) * 4;

  short* sp = (short*)(ws + base_floats);
  short* y_p = sp;                                   sp += (size_t)3 * NN * DD;
  short* attn_p = sp;                                sp += (size_t)3 * NN * DD;
  short* disp_p = sp;                                sp += (size_t)3 * EE * CAPP * DD;
  short* hbuf_p = sp;                                sp += (size_t)3 * EE * CAPP * DFF;
  short* qkvw_p = sp;                                sp += (size_t)3 * LL * 3 * DD * DD;
  short* outw_p = sp;                                sp += (size_t)3 * LL * DD * DD;
  short* ew_p = sp;                                  sp += (size_t)3 * EE * DFF * DD;
  size_t mfma_need = (size_t)((char*)sp - (char*)d_ws);
  bool use_mfma = (ws_size >= mfma_need);
  (void)fb_need;

  embed_kernel<<<TT, 256, 0, stream>>>(input_ids, tok_emb, pos_emb, x);
  sincos_kernel<<<(TT * HALF) / 256, 256, 0, stream>>>(sintab, costab);

  if (use_mfma) {
    long long nq = (long long)LL * 3 * DD * DD;
    long long no = (long long)LL * DD * DD;
    convert_kernel<<<(int)(nq / 2048), 256, 0, stream>>>(qkv_w, qkvw_p, nq);
    convert_kernel<<<(int)(no / 2048), 256, 0, stream>>>(out_w, outw_p, no);
    long long ne = (long long)EE * DFF * DD;

    for (int l = 0; l < LL; l++) {
      int fastf = (l == LL - 1) ? 8 : 0;
      ln_kernel<<<NN, 256, 0, stream>>>(x, y, y_p, ln1_w + l * DD, ln1_b + l * DD);
      gemm_mfma<<<dim3(3 * DD / 128, NN / 128, 1), 256, 0, stream>>>(
          y_p, qkvw_p + (size_t)l * 3 * DD * DD, nullptr, nullptr, qkv,
          NN, 3 * DD, DD, 0, 0, 0, 0, 0,
          (long long)NN * DD, (long long)LL * 3 * DD * DD, 0);
      rope_kernel<<<TT, 256, 0, stream>>>(qkv, sintab, costab);
      attn_kernel<<<512, 256, 0, stream>>>(qkv, attn32, attn_p);
      gemm_mfma<<<dim3(DD / 128, NN / 128, 1), 256, 0, stream>>>(
          attn_p, outw_p + (size_t)l * DD * DD, nullptr, x, x,
          NN, DD, DD, 4, 0, 0, 0, 0,
          (long long)NN * DD, (long long)LL * DD * DD, 0);
      ln_kernel<<<NN, 256, 0, stream>>>(x, y, y_p, ln2_w + l * DD, ln2_b + l * DD);
      router_kernel<<<NN, 64, 0, stream>>>(
          y, router_w + (size_t)l * EE * DD, router_b + l * EE,
          noise_w + (size_t)l * EE * DD, noise_b + l * EE,
          noise + (size_t)l * NN * EE, slot_e, slot_g);
      scan_kernel<<<1, 256, 0, stream>>>(slot_e, slot_pos);
      dispatch_planes_kernel<<<NK, 256, 0, stream>>>(y_p, slot_pos, disp_p);
      convert_kernel<<<(int)(ne / 2048), 256, 0, stream>>>(e_w1 + (size_t)l * ne, ew_p, ne);
      gemm_mfma<<<dim3(DFF / 128, CAPP / 128, EE), 256, 0, stream>>>(
          disp_p, ew_p, e_b1 + (size_t)l * EE * DFF, nullptr, hbuf_p,
          CAPP, DFF, DD, 1 | 2 | 16 | fastf,
          (long long)CAPP * DD, (long long)DFF * DD, DFF, (long long)CAPP * DFF,
          (long long)EE * CAPP * DD, (long long)EE * DFF * DD, (long long)EE * CAPP * DFF);
      convert_kernel<<<(int)(ne / 2048), 256, 0, stream>>>(e_w2 + (size_t)l * ne, ew_p, ne);
      gemm_mfma<<<dim3(DD / 128, CAPP / 128, EE), 256, 0, stream>>>(
          hbuf_p, ew_p, e_b2 + (size_t)l * EE * DD, nullptr, eo,
          CAPP, DD, DFF, 1 | fastf,
          (long long)CAPP * DFF, (long long)DD * DFF, DD, (long long)CAPP * DD,
          (long long)EE * CAPP * DFF, (long long)EE * DD * DFF, 0);
      combine_kernel<<<NN, 256, 0, stream>>>(x, eo, slot_pos, slot_g);
    }
  } else {
    for (int l = 0; l < LL; l++) {
      ln_kernel<<<NN, 256, 0, stream>>>(x, y, nullptr, ln1_w + l * DD, ln1_b + l * DD);
      gemm_kernel<<<dim3(3 * DD / 128, NN / 128, 1), 256, 0, stream>>>(
          y, qkv_w + (size_t)l * 3 * DD * DD, nullptr, nullptr, qkv,
          NN, 3 * DD, DD, 0, 0, 0, 0, 0);
      rope_kernel<<<TT, 256, 0, stream>>>(qkv, sintab, costab);
      attn_kernel<<<512, 256, 0, stream>>>(qkv, attn32, nullptr);
      gemm_kernel<<<dim3(DD / 128, NN / 128, 1), 256, 0, stream>>>(
          attn32, out_w + (size_t)l * DD * DD, nullptr, x, x,
          NN, DD, DD, 4, 0, 0, 0, 0);
      ln_kernel<<<NN, 256, 0, stream>>>(x, y, nullptr, ln2_w + l * DD, ln2_b + l * DD);
      router_kernel<<<NN, 64, 0, stream>>>(
          y, router_w + (size_t)l * EE * DD, router_b + l * EE,
          noise_w + (size_t)l * EE * DD, noise_b + l * EE,
          noise + (size_t)l * NN * EE, slot_e, slot_g);
      scan_kernel<<<1, 256, 0, stream>>>(slot_e, slot_pos);
      dispatch_kernel<<<NK, 256, 0, stream>>>(y, slot_pos, disp32);
      gemm_kernel<<<dim3(DFF / 128, CAPP / 128, EE), 256, 0, stream>>>(
          disp32, e_w1 + (size_t)l * EE * DFF * DD, e_b1 + (size_t)l * EE * DFF, nullptr, hbuf32,
          CAPP, DFF, DD, 3,
          (long long)CAPP * DD, (long long)DFF * DD, DFF, (long long)CAPP * DFF);
      gemm_kernel<<<dim3(DD / 128, CAPP / 128, EE), 256, 0, stream>>>(
          hbuf32, e_w2 + (size_t)l * EE * DD * DFF, e_b2 + (size_t)l * EE * DD, nullptr, eo,
          CAPP, DD, DFF, 1,
          (long long)CAPP * DFF, (long long)DD * DFF, DD, (long long)CAPP * DD);
      combine_kernel<<<NN, 256, 0, stream>>>(x, eo, slot_pos, slot_g);
    }
  }
  ln_kernel<<<NN, 256, 0, stream>>>(x, out, nullptr, lnf_w, lnf_b);
  (void)in_sizes; (void)n_in; (void)out_size; (void)ws_size;
}

// Round 2
// 2558.953 us; speedup vs baseline: 1.1291x; 1.0819x over previous
//
#include <hip/hip_runtime.h>
#include <math.h>

#define TT   2048
#define DD   1024
#define HH   16
#define HSS  64
#define EE   8
#define KTOP 2
#define LL   2
#define CAPP 512
#define NN   2048
#define DFF  4096
#define NK   (NN*KTOP)
#define HALF 32

typedef __attribute__((ext_vector_type(8))) short bf16x8;
typedef __attribute__((ext_vector_type(4))) float f32x4;

// split fp32 v into 3 bf16 planes (RNE bit-math; v = s0 + s1 + s2 to ~2^-27 rel)
__device__ __forceinline__ void split3(float v, short& s0, short& s1, short& s2) {
  union { float f; unsigned u; } a, b0, c, b1, d;
  a.f = v;
  unsigned t0 = (a.u + 0x7fffu + ((a.u >> 16) & 1u)) & 0xffff0000u;
  b0.u = t0;
  float r1 = v - b0.f;
  c.f = r1;
  unsigned t1 = (c.u + 0x7fffu + ((c.u >> 16) & 1u)) & 0xffff0000u;
  b1.u = t1;
  float r2 = r1 - b1.f;
  d.f = r2;
  unsigned t2 = d.u + 0x7fffu + ((d.u >> 16) & 1u);
  s0 = (short)(t0 >> 16); s1 = (short)(t1 >> 16); s2 = (short)(t2 >> 16);
}

// async global->LDS 16B (dest = wave-uniform LDS base + lane*16)
__device__ __forceinline__ void gld16(const short* g, short* l) {
  __builtin_amdgcn_global_load_lds(
      (const __attribute__((address_space(1))) unsigned int*)g,
      (__attribute__((address_space(3))) unsigned int*)l, 16, 0, 0);
}

// ---------------- embedding ----------------
__global__ __launch_bounds__(256) void embed_kernel(const int* __restrict__ ids,
                                                    const float* __restrict__ tok,
                                                    const float* __restrict__ pos,
                                                    float* __restrict__ x) {
  int t = blockIdx.x, tid = threadIdx.x;
  int id = ids[t];
  float4 a = ((const float4*)(tok + (long long)id * DD))[tid];
  float4 b = ((const float4*)(pos + (long long)t * DD))[tid];
  float4 r;
  r.x = a.x + b.x; r.y = a.y + b.y; r.z = a.z + b.z; r.w = a.w + b.w;
  ((float4*)(x + (long long)t * DD))[tid] = r;
}

// ---------------- RoPE sin/cos table ----------------
__global__ __launch_bounds__(256) void sincos_kernel(float* __restrict__ st, float* __restrict__ ct) {
  int idx = blockIdx.x * 256 + threadIdx.x;
  int t = idx >> 5, i = idx & 31;
  double div = exp(-(double)(2 * i) * (9.210340371976184 / 64.0));
  double a = (double)t * div;
  st[idx] = (float)sin(a);
  ct[idx] = (float)cos(a);
}

// ---------------- fp32 -> 3 bf16 plane conversion (8 elems/thread) ----------------
__global__ __launch_bounds__(256) void convert_kernel(const float* __restrict__ in,
                                                      short* __restrict__ out, long long n) {
  long long i = ((long long)blockIdx.x * 256 + threadIdx.x) * 8;
  float4 v0 = *(const float4*)(in + i);
  float4 v1 = *(const float4*)(in + i + 4);
  float vv[8] = {v0.x, v0.y, v0.z, v0.w, v1.x, v1.y, v1.z, v1.w};
  short s0[8], s1[8], s2[8];
#pragma unroll
  for (int j = 0; j < 8; j++) split3(vv[j], s0[j], s1[j], s2[j]);
  *(short4*)(out + i)         = make_short4(s0[0], s0[1], s0[2], s0[3]);
  *(short4*)(out + i + 4)     = make_short4(s0[4], s0[5], s0[6], s0[7]);
  *(short4*)(out + n + i)     = make_short4(s1[0], s1[1], s1[2], s1[3]);
  *(short4*)(out + n + i + 4) = make_short4(s1[4], s1[5], s1[6], s1[7]);
  *(short4*)(out + 2*n + i)   = make_short4(s2[0], s2[1], s2[2], s2[3]);
  *(short4*)(out + 2*n + i+4) = make_short4(s2[4], s2[5], s2[6], s2[7]);
}

// ---------------- layernorm (+ optional bf16x3 plane output) ----------------
__global__ __launch_bounds__(256) void ln_kernel(const float* __restrict__ in, float* __restrict__ out,
                                                 short* __restrict__ yp,
                                                 const float* __restrict__ w, const float* __restrict__ b) {
  int row = blockIdx.x, tid = threadIdx.x;
  float4 v = ((const float4*)(in + (long long)row * DD))[tid];
  float s = v.x + v.y + v.z + v.w;
  float q = v.x * v.x + v.y * v.y + v.z * v.z + v.w * v.w;
#pragma unroll
  for (int off = 32; off > 0; off >>= 1) {
    s += __shfl_down(s, off);
    q += __shfl_down(q, off);
  }
  __shared__ float rs[4], rq[4];
  int wv = tid >> 6;
  if ((tid & 63) == 0) { rs[wv] = s; rq[wv] = q; }
  __syncthreads();
  float S = rs[0] + rs[1] + rs[2] + rs[3];
  float Q = rq[0] + rq[1] + rq[2] + rq[3];
  float mean = S * (1.0f / DD);
  float var = Q * (1.0f / DD) - mean * mean;
  float rstd = rsqrtf(var + 1e-5f);
  float4 wv4 = ((const float4*)w)[tid];
  float4 bv4 = ((const float4*)b)[tid];
  float4 r;
  r.x = (v.x - mean) * rstd * wv4.x + bv4.x;
  r.y = (v.y - mean) * rstd * wv4.y + bv4.y;
  r.z = (v.z - mean) * rstd * wv4.z + bv4.z;
  r.w = (v.w - mean) * rstd * wv4.w + bv4.w;
  ((float4*)(out + (long long)row * DD))[tid] = r;
  if (yp) {
    float rr[4] = {r.x, r.y, r.z, r.w};
    short a0[4], a1[4], a2[4];
#pragma unroll
    for (int j = 0; j < 4; j++) split3(rr[j], a0[j], a1[j], a2[j]);
    size_t off = (size_t)row * DD + tid * 4;
    *(short4*)(yp + off)                    = make_short4(a0[0], a0[1], a0[2], a0[3]);
    *(short4*)(yp + (size_t)NN*DD + off)    = make_short4(a1[0], a1[1], a1[2], a1[3]);
    *(short4*)(yp + (size_t)2*NN*DD + off)  = make_short4(a2[0], a2[1], a2[2], a2[3]);
  }
}

// ---------------- fp32 tiled GEMM (fallback path) ----------------
__global__ __launch_bounds__(256) void gemm_kernel(
    const float* __restrict__ Aall, const float* __restrict__ Ball,
    const float* __restrict__ biasAll, const float* __restrict__ resAll,
    float* __restrict__ Call, int M, int Nn, int Kd, int flags,
    long long sA, long long sB, long long sBias, long long sC) {
  const float* A = Aall + (long long)blockIdx.z * sA;
  const float* B = Ball + (long long)blockIdx.z * sB;
  float* C = Call + (long long)blockIdx.z * sC;
  __shared__ float As[128 * 17];
  __shared__ float Bs[128 * 17];
  int tid = threadIdx.x;
  int tx = tid & 15, ty = tid >> 4;
  int bm = blockIdx.y * 128, bn = blockIdx.x * 128;
  int lrow = tid >> 2;
  int lk = (tid & 3) << 2;
  float acc[8][8];
#pragma unroll
  for (int i = 0; i < 8; i++)
#pragma unroll
    for (int j = 0; j < 8; j++) acc[i][j] = 0.f;
  const float* Arow0 = A + (long long)(bm + lrow) * Kd + lk;
  const float* Arow1 = A + (long long)(bm + lrow + 64) * Kd + lk;
  const float* Brow0 = B + (long long)(bn + lrow) * Kd + lk;
  const float* Brow1 = B + (long long)(bn + lrow + 64) * Kd + lk;
  for (int kb = 0; kb < Kd; kb += 16) {
    float4 a0 = *(const float4*)(Arow0 + kb);
    float4 a1 = *(const float4*)(Arow1 + kb);
    float4 b0 = *(const float4*)(Brow0 + kb);
    float4 b1 = *(const float4*)(Brow1 + kb);
    __syncthreads();
    As[lrow * 17 + lk + 0] = a0.x; As[lrow * 17 + lk + 1] = a0.y;
    As[lrow * 17 + lk + 2] = a0.z; As[lrow * 17 + lk + 3] = a0.w;
    As[(lrow + 64) * 17 + lk + 0] = a1.x; As[(lrow + 64) * 17 + lk + 1] = a1.y;
    As[(lrow + 64) * 17 + lk + 2] = a1.z; As[(lrow + 64) * 17 + lk + 3] = a1.w;
    Bs[lrow * 17 + lk + 0] = b0.x; Bs[lrow * 17 + lk + 1] = b0.y;
    Bs[lrow * 17 + lk + 2] = b0.z; Bs[lrow * 17 + lk + 3] = b0.w;
    Bs[(lrow + 64) * 17 + lk + 0] = b1.x; Bs[(lrow + 64) * 17 + lk + 1] = b1.y;
    Bs[(lrow + 64) * 17 + lk + 2] = b1.z; Bs[(lrow + 64) * 17 + lk + 3] = b1.w;
    __syncthreads();
#pragma unroll
    for (int k = 0; k < 16; k++) {
      float av[8], bv[8];
#pragma unroll
      for (int i = 0; i < 8; i++) av[i] = As[(ty + 16 * i) * 17 + k];
#pragma unroll
      for (int j = 0; j < 8; j++) bv[j] = Bs[(tx + 16 * j) * 17 + k];
#pragma unroll
      for (int i = 0; i < 8; i++)
#pragma unroll
        for (int j = 0; j < 8; j++) acc[i][j] = fmaf(av[i], bv[j], acc[i][j]);
    }
  }
  const float* bias = (flags & 1) ? (biasAll + (long long)blockIdx.z * sBias) : nullptr;
  const float* res = (flags & 4) ? (resAll + (long long)blockIdx.z * sC) : nullptr;
#pragma unroll
  for (int i = 0; i < 8; i++) {
    int row = bm + ty + 16 * i;
#pragma unroll
    for (int j = 0; j < 8; j++) {
      int col = bn + tx + 16 * j;
      float v = acc[i][j];
      if (flags & 1) v += bias[col];
      if (flags & 2) v = fmaxf(v, 0.f);
      if (flags & 4) v += res[(long long)row * Nn + col];
      C[(long long)row * Nn + col] = v;
    }
  }
}

// ---------------- bf16x3 emulated-fp32 MFMA GEMM (m97 structure) ----------------
// C = A(MxK) * B(NxK)^T from pre-split bf16 planes (Ap/Bp: [3][batch][rows][K]).
// flags: 1=bias, 2=relu, 4=residual(fp32 C only), 8=fast(3 products), 16=C as bf16x3 planes,
//        bits 8..15 = splitK (0/1 = none; >1: gridDim.z = batch*splitK, raw fp32 partials
//        written to Call at [(s*NB+e)*sC + row*Nn + col], bias/relu/res deferred to reduce).
// 128x128 tile, 256 thr = 4 waves (2x2 of 64x64), 16x16x32 bf16 MFMA.
// Staging: global_load_lds dwordx4 into linear [3][128][32] shorts (48 KB, 3 blocks/CU),
// chunk-swizzled on the GLOBAL source (c ^ ((row>>1)&3)) so swizzled reads are 2-way-free.
// XCD-aware bijective block swizzle (all grids divisible by 8).
__global__ __launch_bounds__(256, 3) void gemm_mfma(
    const short* __restrict__ Ap, const short* __restrict__ Bp,
    const float* __restrict__ biasAll, const float* __restrict__ resAll,
    void* __restrict__ Call, int M, int Nn, int Kd, int flags,
    long long sA, long long sB, long long sBias, long long sC,
    long long PA, long long PB, long long PC) {
  const bool fast = (flags & 8);
  const int np = fast ? 2 : 3;
  const int splitK = (flags >> 8) & 0xff;
  __shared__ short As[3][128][32];
  __shared__ short Bs[3][128][32];
  int tid = threadIdx.x;

  // ---- XCD-aware swizzle of flattened block index ----
  int gx = gridDim.x, gy = gridDim.y;
  int nwg = gx * gy * gridDim.z;          // always divisible by 8 here
  int flat = blockIdx.x + gx * (blockIdx.y + gy * blockIdx.z);
  int cpx = nwg >> 3;
  int wkid = (flat & 7) * cpx + (flat >> 3);
  int bz = wkid / (gx * gy);
  int rem = wkid - bz * gx * gy;
  int by = rem / gx, bx = rem - by * gx;

  // ---- split-K decode ----
  int sk = 0, e = bz, kLen = Kd;
  if (splitK > 1) { sk = bz % splitK; e = bz / splitK; kLen = Kd / splitK; }
  int k0 = sk * kLen;

  int bm = by * 128, bn = bx * 128;
  long long zA = (long long)e * sA;
  long long zB = (long long)e * sB;

  int wid = tid >> 6, lane = tid & 63;
  int lrow = lane >> 2, lchunk = lane & 3;
  // stored chunk = linear chunk ^ ((row>>1)&3); row = h*64 + wid*16 + lrow,
  // and (row>>1)&3 == (lrow>>1)&3 (h*64, wid*16 are multiples of 16).
  int cs = lchunk ^ ((lrow >> 1) & 3);
  const short* gAbase = Ap + zA + (long long)(bm + wid * 16 + lrow) * Kd + cs * 8;
  const short* gBbase = Bp + zB + (long long)(bn + wid * 16 + lrow) * Kd + cs * 8;
  long long hstepA = (long long)64 * Kd;  // +64 rows

  int wm = (wid & 1) * 64, wn = (wid >> 1) * 64;
  int tr = lane & 15, quad = lane >> 4;
  int qsw = (quad ^ ((tr >> 1) & 3)) << 3;  // swizzled read offset (shorts)

  f32x4 acc[4][4];
#pragma unroll
  for (int i = 0; i < 4; i++)
#pragma unroll
    for (int j = 0; j < 4; j++) acc[i][j] = (f32x4){0.f, 0.f, 0.f, 0.f};

  for (int kb = k0; kb < k0 + kLen; kb += 32) {
    __syncthreads();
#pragma unroll
    for (int p = 0; p < 3; p++) {
      if (p < np) {
#pragma unroll
        for (int h = 0; h < 2; h++) {
          int rb = h * 64 + wid * 16;
          gld16(gAbase + p * PA + h * hstepA + kb, &As[p][rb][0]);
          gld16(gBbase + p * PB + h * hstepA + kb, &Bs[p][rb][0]);
        }
      }
    }
    __syncthreads();   // compiler drains vmcnt(0) here: LDS tile ready
    bf16x8 af[4][3];
#pragma unroll
    for (int mi = 0; mi < 4; mi++) {
      int ar = wm + mi * 16 + tr;
      af[mi][0] = *(const bf16x8*)&As[0][ar][qsw];
      af[mi][1] = *(const bf16x8*)&As[1][ar][qsw];
      af[mi][2] = fast ? af[mi][0] : *(const bf16x8*)&As[2][ar][qsw];
    }
#pragma unroll
    for (int nj = 0; nj < 4; nj++) {
      int br = wn + nj * 16 + tr;
      bf16x8 b0 = *(const bf16x8*)&Bs[0][br][qsw];
      bf16x8 b1 = *(const bf16x8*)&Bs[1][br][qsw];
      bf16x8 b2 = fast ? b0 : *(const bf16x8*)&Bs[2][br][qsw];
#pragma unroll
      for (int mi = 0; mi < 4; mi++) {
        f32x4 c = acc[mi][nj];
        c = __builtin_amdgcn_mfma_f32_16x16x32_bf16(af[mi][1], b0, c, 0, 0, 0); // a1b0
        c = __builtin_amdgcn_mfma_f32_16x16x32_bf16(af[mi][0], b1, c, 0, 0, 0); // a0b1
        if (!fast) {
          c = __builtin_amdgcn_mfma_f32_16x16x32_bf16(af[mi][2], b0, c, 0, 0, 0); // a2b0
          c = __builtin_amdgcn_mfma_f32_16x16x32_bf16(af[mi][1], b1, c, 0, 0, 0); // a1b1
          c = __builtin_amdgcn_mfma_f32_16x16x32_bf16(af[mi][0], b2, c, 0, 0, 0); // a0b2
        }
        c = __builtin_amdgcn_mfma_f32_16x16x32_bf16(af[mi][0], b0, c, 0, 0, 0);   // a0b0
        acc[mi][nj] = c;
      }
    }
  }

  long long z = e;
  if (splitK > 1) {
    // raw fp32 partials; bias/relu/res applied by reduce_kernel
    int NB = nwg / (gx * gy) / splitK;
    float* P = (float*)Call;
    long long base = ((long long)sk * NB + e) * sC;
#pragma unroll
    for (int mi = 0; mi < 4; mi++)
#pragma unroll
      for (int nj = 0; nj < 4; nj++) {
        int col = bn + wn + nj * 16 + tr;
#pragma unroll
        for (int rg = 0; rg < 4; rg++) {
          int row = bm + wm + mi * 16 + quad * 4 + rg;
          P[base + (long long)row * Nn + col] = acc[mi][nj][rg];
        }
      }
    return;
  }
  const float* bias = (flags & 1) ? (biasAll + z * sBias) : nullptr;
  if (flags & 16) {
    short* Cs = (short*)Call;
#pragma unroll
    for (int mi = 0; mi < 4; mi++)
#pragma unroll
      for (int nj = 0; nj < 4; nj++) {
        int col = bn + wn + nj * 16 + tr;
#pragma unroll
        for (int rg = 0; rg < 4; rg++) {
          int row = bm + wm + mi * 16 + quad * 4 + rg;
          float v = acc[mi][nj][rg];
          if (flags & 1) v += bias[col];
          if (flags & 2) v = fmaxf(v, 0.f);
          short s0, s1, s2;
          split3(v, s0, s1, s2);
          long long off = z * sC + (long long)row * Nn + col;
          Cs[off] = s0; Cs[PC + off] = s1; Cs[2 * PC + off] = s2;
        }
      }
  } else {
    float* C = (float*)Call;
    const float* res = (flags & 4) ? (resAll + z * sC) : nullptr;
#pragma unroll
    for (int mi = 0; mi < 4; mi++)
#pragma unroll
      for (int nj = 0; nj < 4; nj++) {
        int col = bn + wn + nj * 16 + tr;
#pragma unroll
        for (int rg = 0; rg < 4; rg++) {
          int row = bm + wm + mi * 16 + quad * 4 + rg;
          float v = acc[mi][nj][rg];
          if (flags & 1) v += bias[col];
          if (flags & 2) v = fmaxf(v, 0.f);
          if (flags & 4) v += res[(long long)row * Nn + col];
          C[z * sC + (long long)row * Nn + col] = v;
        }
      }
  }
  (void)M;
}

// ---------------- split-K reduce: dst = sum_s part[s] (+bias) (+dst as residual) ----------------
// flags: 1=bias (per-batch stride sBias, col = i % Nn, batch = i / MNn), 4=residual (dst preloaded)
__global__ __launch_bounds__(256) void reduce_kernel(
    float* __restrict__ dst, const float* __restrict__ part,
    const float* __restrict__ biasAll, int splits, long long total,
    int Nn, long long MNn, long long sBias, int flags) {
  long long i = ((long long)blockIdx.x * 256 + threadIdx.x) * 4;
  if (i >= total) return;
  float4 v = make_float4(0.f, 0.f, 0.f, 0.f);
  for (int s = 0; s < splits; s++) {
    float4 p = *(const float4*)(part + (long long)s * total + i);
    v.x += p.x; v.y += p.y; v.z += p.z; v.w += p.w;
  }
  if (flags & 1) {
    long long e = i / MNn;
    int col = (int)(i % Nn);
    const float* b = biasAll + e * sBias + col;
    v.x += b[0]; v.y += b[1]; v.z += b[2]; v.w += b[3];
  }
  if (flags & 4) {
    float4 r = *(const float4*)(dst + i);
    v.x += r.x; v.y += r.y; v.z += r.z; v.w += r.w;
  }
  *(float4*)(dst + i) = v;
}

// ---------------- RoPE in place ----------------
__global__ __launch_bounds__(256) void rope_kernel(float* __restrict__ qkv,
                                                   const float* __restrict__ st,
                                                   const float* __restrict__ ct) {
  int t = blockIdx.x, tid = threadIdx.x;
#pragma unroll
  for (int p = tid; p < HH * HALF; p += 256) {
    int h = p >> 5, i = p & 31;
    float s = st[t * HALF + i], c = ct[t * HALF + i];
    float* q = qkv + (long long)t * (3 * DD) + h * HSS;
    float q1 = q[i], q2 = q[i + HALF];
    q[i] = q1 * c - q2 * s;
    q[i + HALF] = q2 * c + q1 * s;
    float* k = q + DD;
    float k1 = k[i], k2 = k[i + HALF];
    k[i] = k1 * c - k2 * s;
    k[i + HALF] = k2 * c + k1 * s;
  }
}

// ---------------- flash attention: key-split across 4 waves ----------------
__global__ __launch_bounds__(256, 1) void attn_kernel(const float* __restrict__ qkv,
                                                      float* __restrict__ attn,
                                                      short* __restrict__ ap) {
  int bid = blockIdx.x;
  int head = bid & 15;
  int qc = (bid < 256) ? (31 - (bid >> 4)) : ((bid - 256) >> 4);
  int tid = threadIdx.x;
  int w = tid >> 6;
  int r = tid & 63;
  int qrow = qc * 64 + r;
  int nkt = qc + 1;

  __shared__ float4 KVbuf[4][2][16][16];
  __shared__ float Ms[4][64];
  __shared__ float Ls[4][64];

  float4 q[16], o[16];
  const float4* qp = (const float4*)(qkv + (long long)qrow * (3 * DD) + head * HSS);
#pragma unroll
  for (int d = 0; d < 16; d++) { q[d] = qp[d]; o[d] = make_float4(0.f, 0.f, 0.f, 0.f); }
  float m = -INFINITY, l = 0.f;

  for (int kt = w; kt < nkt; kt += 4) {
    bool diag = (kt == qc);
#pragma unroll 1
    for (int s = 0; s < 4; s++) {
      int kbase = kt * 64 + s * 16;
#pragma unroll
      for (int it = 0; it < 4; it++) {
        int fid = r + it * 64;
        int krow = fid >> 4, d4 = fid & 15;
        const float* bK = qkv + (long long)(kbase + krow) * (3 * DD) + DD + head * HSS + d4 * 4;
        KVbuf[w][0][krow][d4] = *(const float4*)bK;
        KVbuf[w][1][krow][d4] = *(const float4*)(bK + DD);
      }
      float sbuf[16];
#pragma unroll
      for (int jj = 0; jj < 16; jj++) {
        const float4* kr = KVbuf[w][0][jj];
        float sv = 0.f;
#pragma unroll
        for (int d = 0; d < 16; d++) {
          float4 kv = kr[d];
          sv = fmaf(q[d].x, kv.x, sv); sv = fmaf(q[d].y, kv.y, sv);
          sv = fmaf(q[d].z, kv.z, sv); sv = fmaf(q[d].w, kv.w, sv);
        }
        sv *= 0.125f;
        if (diag && (kbase + jj > qrow)) sv = -1e30f;
        sbuf[jj] = sv;
      }
      float gm = m;
#pragma unroll
      for (int jj = 0; jj < 16; jj++) gm = fmaxf(gm, sbuf[jj]);
      float scale = __expf(m - gm);
      m = gm;
      l *= scale;
#pragma unroll
      for (int d = 0; d < 16; d++) {
        o[d].x *= scale; o[d].y *= scale; o[d].z *= scale; o[d].w *= scale;
      }
#pragma unroll
      for (int jj = 0; jj < 16; jj++) {
        float p = __expf(sbuf[jj] - m);
        l += p;
        const float4* vr = KVbuf[w][1][jj];
#pragma unroll
        for (int d = 0; d < 16; d++) {
          float4 vv = vr[d];
          o[d].x = fmaf(p, vv.x, o[d].x); o[d].y = fmaf(p, vv.y, o[d].y);
          o[d].z = fmaf(p, vv.z, o[d].z); o[d].w = fmaf(p, vv.w, o[d].w);
        }
      }
    }
  }

  typedef float4 OscRow[64][5];
  OscRow* Osc = reinterpret_cast<OscRow*>(&KVbuf[0][0][0][0]);
  int rr = tid & 63, ii = tid >> 6;
  long long obase = (long long)head * TT * HSS + (long long)(qc * 64 + rr) * HSS;
#pragma unroll
  for (int c = 0; c < 4; c++) {
    __syncthreads();
    Osc[w][r][0] = o[c * 4 + 0];
    Osc[w][r][1] = o[c * 4 + 1];
    Osc[w][r][2] = o[c * 4 + 2];
    Osc[w][r][3] = o[c * 4 + 3];
    if (c == 0) { Ms[w][r] = m; Ls[w][r] = l; }
    __syncthreads();
    float m0 = Ms[0][rr], m1 = Ms[1][rr], m2 = Ms[2][rr], m3 = Ms[3][rr];
    float M = fmaxf(fmaxf(m0, m1), fmaxf(m2, m3));
    float s0 = __expf(m0 - M), s1 = __expf(m1 - M);
    float s2 = __expf(m2 - M), s3 = __expf(m3 - M);
    float L = s0 * Ls[0][rr] + s1 * Ls[1][rr] + s2 * Ls[2][rr] + s3 * Ls[3][rr];
    float rl = 1.f / L;
    float4 a0 = Osc[0][rr][ii], a1 = Osc[1][rr][ii];
    float4 a2 = Osc[2][rr][ii], a3 = Osc[3][rr][ii];
    float4 res;
    res.x = (s0 * a0.x + s1 * a1.x + s2 * a2.x + s3 * a3.x) * rl;
    res.y = (s0 * a0.y + s1 * a1.y + s2 * a2.y + s3 * a3.y) * rl;
    res.z = (s0 * a0.z + s1 * a1.z + s2 * a2.z + s3 * a3.z) * rl;
    res.w = (s0 * a0.w + s1 * a1.w + s2 * a2.w + s3 * a3.w) * rl;
    long long oaddr = obase + c * 16 + ii * 4;
    *(float4*)(attn + oaddr) = res;
    if (ap) {
      float rv[4] = {res.x, res.y, res.z, res.w};
      short p0[4], p1[4], p2[4];
#pragma unroll
      for (int j = 0; j < 4; j++) split3(rv[j], p0[j], p1[j], p2[j]);
      *(short4*)(ap + oaddr)                    = make_short4(p0[0], p0[1], p0[2], p0[3]);
      *(short4*)(ap + (size_t)NN*DD + oaddr)    = make_short4(p1[0], p1[1], p1[2], p1[3]);
      *(short4*)(ap + (size_t)2*NN*DD + oaddr)  = make_short4(p2[0], p2[1], p2[2], p2[3]);
    }
  }
}

// ---------------- router ----------------
__global__ __launch_bounds__(64) void router_kernel(
    const float* __restrict__ y, const float* __restrict__ rw, const float* __restrict__ rb,
    const float* __restrict__ nw, const float* __restrict__ nb, const float* __restrict__ noise,
    int* __restrict__ slot_e, float* __restrict__ slot_g) {
  int n = blockIdx.x;
  int lane = threadIdx.x;
  double accr[EE], accn[EE];
#pragma unroll
  for (int e = 0; e < EE; e++) { accr[e] = 0.0; accn[e] = 0.0; }
  for (int j = 0; j < 16; j++) {
    float xv = y[(long long)n * DD + j * 64 + lane];
#pragma unroll
    for (int e = 0; e < EE; e++) {
      accr[e] += (double)xv * (double)rw[e * DD + j * 64 + lane];
      accn[e] += (double)xv * (double)nw[e * DD + j * 64 + lane];
    }
  }
#pragma unroll
  for (int e = 0; e < EE; e++) {
    for (int off = 32; off > 0; off >>= 1) {
      accr[e] += __shfl_down(accr[e], off);
      accn[e] += __shfl_down(accn[e], off);
    }
  }
  if (lane == 0) {
    float noisy[EE];
#pragma unroll
    for (int e = 0; e < EE; e++) {
      float lg = (float)accr[e] + rb[e];
      float nl = (float)accn[e] + nb[e];
      float sp = (nl > 0.f) ? (nl + log1pf(expf(-nl))) : log1pf(expf(nl));
      noisy[e] = lg + noise[n * EE + e] * sp;
    }
    int i0 = 0;
#pragma unroll
    for (int e = 1; e < EE; e++) if (noisy[e] > noisy[i0]) i0 = e;
    int i1 = -1;
#pragma unroll
    for (int e = 0; e < EE; e++) {
      if (e == i0) continue;
      if (i1 < 0 || noisy[e] > noisy[i1]) i1 = e;
    }
    float v0 = noisy[i0], v1 = noisy[i1];
    float e1 = __expf(v1 - v0);
    float inv = 1.f / (1.f + e1);
    slot_e[2 * n] = i0; slot_e[2 * n + 1] = i1;
    slot_g[2 * n] = inv; slot_g[2 * n + 1] = e1 * inv;
  }
}

// ---------------- deterministic rank scan ----------------
__global__ __launch_bounds__(256) void scan_kernel(const int* __restrict__ slot_e,
                                                   int* __restrict__ slot_pos) {
  __shared__ int cnt[256 * EE];
  int tid = threadIdx.x;
  int base = tid * 16;
  int c[EE];
#pragma unroll
  for (int e = 0; e < EE; e++) c[e] = 0;
  int loc[16];
  for (int i = 0; i < 16; i++) {
    int e = slot_e[base + i];
    loc[i] = e;
    c[e]++;
  }
#pragma unroll
  for (int e = 0; e < EE; e++) cnt[tid * EE + e] = c[e];
  __syncthreads();
  if (tid < EE) {
    int run = 0;
    for (int t2 = 0; t2 < 256; t2++) {
      int v = cnt[t2 * EE + tid];
      cnt[t2 * EE + tid] = run;
      run += v;
    }
  }
  __syncthreads();
  int run[EE];
#pragma unroll
  for (int e = 0; e < EE; e++) run[e] = cnt[tid * EE + e];
  for (int i = 0; i < 16; i++) {
    int e = loc[i];
    int r = run[e]++;
    slot_pos[base + i] = (r < CAPP) ? (e * CAPP + r) : -1;
  }
}

// ---------------- dispatch (fp32 fallback) ----------------
__global__ __launch_bounds__(256) void dispatch_kernel(const float* __restrict__ y,
                                                       const int* __restrict__ slot_pos,
                                                       float* __restrict__ disp) {
  int i = blockIdx.x;
  int pos = slot_pos[i];
  if (pos < 0) return;
  int tok = i >> 1;
  ((float4*)(disp + (long long)pos * DD))[threadIdx.x] =
      ((const float4*)(y + (long long)tok * DD))[threadIdx.x];
}

// ---------------- dispatch (bf16x3 planes) ----------------
__global__ __launch_bounds__(256) void dispatch_planes_kernel(const short* __restrict__ yp,
                                                              const int* __restrict__ slot_pos,
                                                              short* __restrict__ dp) {
  int i = blockIdx.x;
  int pos = slot_pos[i];
  if (pos < 0) return;
  int tok = i >> 1;
#pragma unroll
  for (int p = 0; p < 3; p++) {
    short4 v = ((const short4*)(yp + (size_t)p * NN * DD + (size_t)tok * DD))[threadIdx.x];
    ((short4*)(dp + (size_t)p * EE * CAPP * DD + (size_t)pos * DD))[threadIdx.x] = v;
  }
}

// ---------------- combine ----------------
__global__ __launch_bounds__(256) void combine_kernel(float* __restrict__ x,
                                                      const float* __restrict__ eo,
                                                      const int* __restrict__ slot_pos,
                                                      const float* __restrict__ slot_g) {
  int n = blockIdx.x, tid = threadIdx.x;
  int p0 = slot_pos[2 * n], p1 = slot_pos[2 * n + 1];
  float g0 = slot_g[2 * n], g1 = slot_g[2 * n + 1];
  float4 v = ((float4*)(x + (long long)n * DD))[tid];
  if (p0 >= 0) {
    float4 e0 = ((const float4*)(eo + (long long)p0 * DD))[tid];
    v.x = fmaf(g0, e0.x, v.x); v.y = fmaf(g0, e0.y, v.y);
    v.z = fmaf(g0, e0.z, v.z); v.w = fmaf(g0, e0.w, v.w);
  }
  if (p1 >= 0) {
    float4 e1 = ((const float4*)(eo + (long long)p1 * DD))[tid];
    v.x = fmaf(g1, e1.x, v.x); v.y = fmaf(g1, e1.y, v.y);
    v.z = fmaf(g1, e1.z, v.z); v.w = fmaf(g1, e1.w, v.w);
  }
  ((float4*)(x + (long long)n * DD))[tid] = v;
}

extern "C" void kernel_launch(void* const* d_in, const int* in_sizes, int n_in,
                              void* d_out, int out_size, void* d_ws, size_t ws_size,
                              hipStream_t stream) {
  const int* input_ids = (const int*)d_in[0];
  const float* noise = (const float*)d_in[1];
  const float* tok_emb = (const float*)d_in[2];
  const float* pos_emb = (const float*)d_in[3];
  const float* ln1_w = (const float*)d_in[4];
  const float* ln1_b = (const float*)d_in[5];
  const float* ln2_w = (const float*)d_in[6];
  const float* ln2_b = (const float*)d_in[7];
  const float* qkv_w = (const float*)d_in[8];
  const float* out_w = (const float*)d_in[9];
  const float* router_w = (const float*)d_in[10];
  const float* router_b = (const float*)d_in[11];
  const float* noise_w = (const float*)d_in[12];
  const float* noise_b = (const float*)d_in[13];
  const float* e_w1 = (const float*)d_in[14];
  const float* e_b1 = (const float*)d_in[15];
  const float* e_w2 = (const float*)d_in[16];
  const float* e_b2 = (const float*)d_in[17];
  const float* lnf_w = (const float*)d_in[18];
  const float* lnf_b = (const float*)d_in[19];
  float* out = (float*)d_out;

  // ---- workspace layout ----
  float* ws = (float*)d_ws;
  size_t off = 0;
  float* x = ws + off;       off += (size_t)NN * DD;
  float* y = ws + off;       off += (size_t)NN * DD;
  float* qkv = ws + off;     off += (size_t)NN * 3 * DD;
  float* eo = ws + off;      off += (size_t)EE * CAPP * DD;
  float* sintab = ws + off;  off += (size_t)TT * HALF;
  float* costab = ws + off;  off += (size_t)TT * HALF;
  float* attn32 = ws + off;  off += (size_t)NN * DD;
  int* slot_e = (int*)(ws + off);   off += NK;
  int* slot_pos = (int*)(ws + off); off += NK;
  float* slot_g = ws + off;  off += NK;
  size_t base_floats = off;
  float* disp32 = ws + off;
  float* hbuf32 = disp32 + (size_t)EE * CAPP * DD;
  size_t fb_need = (base_floats + (size_t)EE * CAPP * DD + (size_t)EE * CAPP * DFF) * 4;

  short* sp = (short*)(ws + base_floats);
  short* y_p = sp;                                   sp += (size_t)3 * NN * DD;
  short* attn_p = sp;                                sp += (size_t)3 * NN * DD;
  short* disp_p = sp;                                sp += (size_t)3 * EE * CAPP * DD;
  short* hbuf_p = sp;                                sp += (size_t)3 * EE * CAPP * DFF;
  short* qkvw_p = sp;                                sp += (size_t)3 * LL * 3 * DD * DD;
  short* outw_p = sp;                                sp += (size_t)3 * LL * DD * DD;
  short* ew_p = sp;                                  sp += (size_t)3 * EE * DFF * DD;
  size_t mfma_need = (size_t)((char*)sp - (char*)d_ws);
  bool use_mfma = (ws_size >= mfma_need);
  (void)fb_need;

  // split-K partial buffers (reuse regions that are dead at the point of use):
  // - QKV partials (2 x NN x 3DD fp32 = 50.3 MB) and attn-out partials (4 x NN x DD = 33.5 MB)
  //   live in hbuf_p (100.7 MB; only used between MoE-GEMM1 and MoE-GEMM2).
  // - MoE-GEMM2 partials (2 x EE x CAPP x DD = 33.5 MB) live in y..qkv (contiguous
  //   4 x NN x DD fp32; both dead during MoE-GEMM2). Note 2*EE*CAPP*DD == 4*NN*DD.
  float* pQKV = (float*)hbuf_p;
  float* pAO  = (float*)hbuf_p;
  float* pM2  = y;

  embed_kernel<<<TT, 256, 0, stream>>>(input_ids, tok_emb, pos_emb, x);
  sincos_kernel<<<(TT * HALF) / 256, 256, 0, stream>>>(sintab, costab);

  if (use_mfma) {
    long long nq = (long long)LL * 3 * DD * DD;
    long long no = (long long)LL * DD * DD;
    convert_kernel<<<(int)(nq / 2048), 256, 0, stream>>>(qkv_w, qkvw_p, nq);
    convert_kernel<<<(int)(no / 2048), 256, 0, stream>>>(out_w, outw_p, no);
    long long ne = (long long)EE * DFF * DD;

    for (int l = 0; l < LL; l++) {
      int fastf = (l == LL - 1) ? 8 : 0;
      ln_kernel<<<NN, 256, 0, stream>>>(x, y, y_p, ln1_w + l * DD, ln1_b + l * DD);
      // QKV: split-K=2 -> 768 blocks (3 blk/CU); raw partials into hbuf_p
      gemm_mfma<<<dim3(3 * DD / 128, NN / 128, 2), 256, 0, stream>>>(
          y_p, qkvw_p + (size_t)l * 3 * DD * DD, nullptr, nullptr, pQKV,
          NN, 3 * DD, DD, (2 << 8), 0, 0, 0, (long long)NN * 3 * DD,
          (long long)NN * DD, (long long)LL * 3 * DD * DD, 0);
      reduce_kernel<<<(int)((long long)NN * 3 * DD / 1024), 256, 0, stream>>>(
          qkv, pQKV, nullptr, 2, (long long)NN * 3 * DD, 3 * DD,
          (long long)NN * 3 * DD, 0, 0);
      rope_kernel<<<TT, 256, 0, stream>>>(qkv, sintab, costab);
      attn_kernel<<<512, 256, 0, stream>>>(qkv, attn32, attn_p);
      // attn-out: split-K=4 -> 512 blocks (2 blk/CU); residual applied in reduce
      gemm_mfma<<<dim3(DD / 128, NN / 128, 4), 256, 0, stream>>>(
          attn_p, outw_p + (size_t)l * DD * DD, nullptr, nullptr, pAO,
          NN, DD, DD, (4 << 8), 0, 0, 0, (long long)NN * DD,
          (long long)NN * DD, (long long)LL * DD * DD, 0);
      reduce_kernel<<<(int)((long long)NN * DD / 1024), 256, 0, stream>>>(
          x, pAO, nullptr, 4, (long long)NN * DD, DD, (long long)NN * DD, 0, 4);
      ln_kernel<<<NN, 256, 0, stream>>>(x, y, y_p, ln2_w + l * DD, ln2_b + l * DD);
      router_kernel<<<NN, 64, 0, stream>>>(
          y, router_w + (size_t)l * EE * DD, router_b + l * EE,
          noise_w + (size_t)l * EE * DD, noise_b + l * EE,
          noise + (size_t)l * NN * EE, slot_e, slot_g);
      scan_kernel<<<1, 256, 0, stream>>>(slot_e, slot_pos);
      dispatch_planes_kernel<<<NK, 256, 0, stream>>>(y_p, slot_pos, disp_p);
      convert_kernel<<<(int)(ne / 2048), 256, 0, stream>>>(e_w1 + (size_t)l * ne, ew_p, ne);
      gemm_mfma<<<dim3(DFF / 128, CAPP / 128, EE), 256, 0, stream>>>(
          disp_p, ew_p, e_b1 + (size_t)l * EE * DFF, nullptr, hbuf_p,
          CAPP, DFF, DD, 1 | 2 | 16 | fastf,
          (long long)CAPP * DD, (long long)DFF * DD, DFF, (long long)CAPP * DFF,
          (long long)EE * CAPP * DD, (long long)EE * DFF * DD, (long long)EE * CAPP * DFF);
      convert_kernel<<<(int)(ne / 2048), 256, 0, stream>>>(e_w2 + (size_t)l * ne, ew_p, ne);
      // MoE-GEMM2: split-K=2 -> 512 blocks (2 blk/CU); partials in y..qkv; bias in reduce
      gemm_mfma<<<dim3(DD / 128, CAPP / 128, EE * 2), 256, 0, stream>>>(
          hbuf_p, ew_p, nullptr, nullptr, pM2,
          CAPP, DD, DFF, fastf | (2 << 8),
          (long long)CAPP * DFF, (long long)DD * DFF, 0, (long long)CAPP * DD,
          (long long)EE * CAPP * DFF, (long long)EE * DD * DFF, 0);
      reduce_kernel<<<(int)((long long)EE * CAPP * DD / 1024), 256, 0, stream>>>(
          eo, pM2, e_b2 + (size_t)l * EE * DD, 2, (long long)EE * CAPP * DD, DD,
          (long long)CAPP * DD, DD, 1);
      combine_kernel<<<NN, 256, 0, stream>>>(x, eo, slot_pos, slot_g);
    }
  } else {
    for (int l = 0; l < LL; l++) {
      ln_kernel<<<NN, 256, 0, stream>>>(x, y, nullptr, ln1_w + l * DD, ln1_b + l * DD);
      gemm_kernel<<<dim3(3 * DD / 128, NN / 128, 1), 256, 0, stream>>>(
          y, qkv_w + (size_t)l * 3 * DD * DD, nullptr, nullptr, qkv,
          NN, 3 * DD, DD, 0, 0, 0, 0, 0);
      rope_kernel<<<TT, 256, 0, stream>>>(qkv, sintab, costab);
      attn_kernel<<<512, 256, 0, stream>>>(qkv, attn32, nullptr);
      gemm_kernel<<<dim3(DD / 128, NN / 128, 1), 256, 0, stream>>>(
          attn32, out_w + (size_t)l * DD * DD, nullptr, x, x,
          NN, DD, DD, 4, 0, 0, 0, 0);
      ln_kernel<<<NN, 256, 0, stream>>>(x, y, nullptr, ln2_w + l * DD, ln2_b + l * DD);
      router_kernel<<<NN, 64, 0, stream>>>(
          y, router_w + (size_t)l * EE * DD, router_b + l * EE,
          noise_w + (size_t)l * EE * DD, noise_b + l * EE,
          noise + (size_t)l * NN * EE, slot_e, slot_g);
      scan_kernel<<<1, 256, 0, stream>>>(slot_e, slot_pos);
      dispatch_kernel<<<NK, 256, 0, stream>>>(y, slot_pos, disp32);
      gemm_kernel<<<dim3(DFF / 128, CAPP / 128, EE), 256, 0, stream>>>(
          disp32, e_w1 + (size_t)l * EE * DFF * DD, e_b1 + (size_t)l * EE * DFF, nullptr, hbuf32,
          CAPP, DFF, DD, 3,
          (long long)CAPP * DD, (long long)DFF * DD, DFF, (long long)CAPP * DFF);
      gemm_kernel<<<dim3(DD / 128, CAPP / 128, EE), 256, 0, stream>>>(
          hbuf32, e_w2 + (size_t)l * EE * DD * DFF, e_b2 + (size_t)l * EE * DD, nullptr, eo,
          CAPP, DD, DFF, 1,
          (long long)CAPP * DFF, (long long)DD * DFF, DD, (long long)CAPP * DD);
      combine_kernel<<<NN, 256, 0, stream>>>(x, eo, slot_pos, slot_g);
    }
  }
  ln_kernel<<<NN, 256, 0, stream>>>(x, out, nullptr, lnf_w, lnf_b);
  (void)in_sizes; (void)n_in; (void)out_size; (void)ws_size;
}

// Round 3
// 2058.090 us; speedup vs baseline: 1.4038x; 1.2434x over previous
//
#include <hip/hip_runtime.h>
#include <math.h>

#define TT   2048
#define DD   1024
#define HH   16
#define HSS  64
#define EE   8
#define KTOP 2
#define LL   2
#define CAPP 512
#define NN   2048
#define DFF  4096
#define NK   (NN*KTOP)
#define HALF 32

typedef __attribute__((ext_vector_type(8))) short bf16x8;
typedef __attribute__((ext_vector_type(4))) float f32x4;

// split fp32 v into 3 bf16 planes (RNE bit-math; v = s0 + s1 + s2 to ~2^-27 rel)
__device__ __forceinline__ void split3(float v, short& s0, short& s1, short& s2) {
  union { float f; unsigned u; } a, b0, c, b1, d;
  a.f = v;
  unsigned t0 = (a.u + 0x7fffu + ((a.u >> 16) & 1u)) & 0xffff0000u;
  b0.u = t0;
  float r1 = v - b0.f;
  c.f = r1;
  unsigned t1 = (c.u + 0x7fffu + ((c.u >> 16) & 1u)) & 0xffff0000u;
  b1.u = t1;
  float r2 = r1 - b1.f;
  d.f = r2;
  unsigned t2 = d.u + 0x7fffu + ((d.u >> 16) & 1u);
  s0 = (short)(t0 >> 16); s1 = (short)(t1 >> 16); s2 = (short)(t2 >> 16);
}

// split fp32 v into 2 bf16 planes (v ~= s0 + s1 to ~2^-16 rel)
__device__ __forceinline__ void split2(float v, short& s0, short& s1) {
  union { float f; unsigned u; } a, b0, c;
  a.f = v;
  unsigned t0 = (a.u + 0x7fffu + ((a.u >> 16) & 1u)) & 0xffff0000u;
  b0.u = t0;
  float r1 = v - b0.f;
  c.f = r1;
  unsigned t1 = c.u + 0x7fffu + ((c.u >> 16) & 1u);
  s0 = (short)(t0 >> 16); s1 = (short)(t1 >> 16);
}

// async global->LDS 16B (dest = wave-uniform LDS base + lane*16)
__device__ __forceinline__ void gld16(const short* g, short* l) {
  __builtin_amdgcn_global_load_lds(
      (const __attribute__((address_space(1))) unsigned int*)g,
      (__attribute__((address_space(3))) unsigned int*)l, 16, 0, 0);
}

// ---------------- embedding ----------------
__global__ __launch_bounds__(256) void embed_kernel(const int* __restrict__ ids,
                                                    const float* __restrict__ tok,
                                                    const float* __restrict__ pos,
                                                    float* __restrict__ x) {
  int t = blockIdx.x, tid = threadIdx.x;
  int id = ids[t];
  float4 a = ((const float4*)(tok + (long long)id * DD))[tid];
  float4 b = ((const float4*)(pos + (long long)t * DD))[tid];
  float4 r;
  r.x = a.x + b.x; r.y = a.y + b.y; r.z = a.z + b.z; r.w = a.w + b.w;
  ((float4*)(x + (long long)t * DD))[tid] = r;
}

// ---------------- RoPE sin/cos table ----------------
__global__ __launch_bounds__(256) void sincos_kernel(float* __restrict__ st, float* __restrict__ ct) {
  int idx = blockIdx.x * 256 + threadIdx.x;
  int t = idx >> 5, i = idx & 31;
  double div = exp(-(double)(2 * i) * (9.210340371976184 / 64.0));
  double a = (double)t * div;
  st[idx] = (float)sin(a);
  ct[idx] = (float)cos(a);
}

// ---------------- fp32 -> 3 bf16 plane conversion (8 elems/thread) ----------------
__global__ __launch_bounds__(256) void convert_kernel(const float* __restrict__ in,
                                                      short* __restrict__ out, long long n) {
  long long i = ((long long)blockIdx.x * 256 + threadIdx.x) * 8;
  float4 v0 = *(const float4*)(in + i);
  float4 v1 = *(const float4*)(in + i + 4);
  float vv[8] = {v0.x, v0.y, v0.z, v0.w, v1.x, v1.y, v1.z, v1.w};
  short s0[8], s1[8], s2[8];
#pragma unroll
  for (int j = 0; j < 8; j++) split3(vv[j], s0[j], s1[j], s2[j]);
  *(short4*)(out + i)         = make_short4(s0[0], s0[1], s0[2], s0[3]);
  *(short4*)(out + i + 4)     = make_short4(s0[4], s0[5], s0[6], s0[7]);
  *(short4*)(out + n + i)     = make_short4(s1[0], s1[1], s1[2], s1[3]);
  *(short4*)(out + n + i + 4) = make_short4(s1[4], s1[5], s1[6], s1[7]);
  *(short4*)(out + 2*n + i)   = make_short4(s2[0], s2[1], s2[2], s2[3]);
  *(short4*)(out + 2*n + i+4) = make_short4(s2[4], s2[5], s2[6], s2[7]);
}

// ---------------- layernorm (+ optional bf16x3 plane output) ----------------
__global__ __launch_bounds__(256) void ln_kernel(const float* __restrict__ in, float* __restrict__ out,
                                                 short* __restrict__ yp,
                                                 const float* __restrict__ w, const float* __restrict__ b) {
  int row = blockIdx.x, tid = threadIdx.x;
  float4 v = ((const float4*)(in + (long long)row * DD))[tid];
  float s = v.x + v.y + v.z + v.w;
  float q = v.x * v.x + v.y * v.y + v.z * v.z + v.w * v.w;
#pragma unroll
  for (int off = 32; off > 0; off >>= 1) {
    s += __shfl_down(s, off);
    q += __shfl_down(q, off);
  }
  __shared__ float rs[4], rq[4];
  int wv = tid >> 6;
  if ((tid & 63) == 0) { rs[wv] = s; rq[wv] = q; }
  __syncthreads();
  float S = rs[0] + rs[1] + rs[2] + rs[3];
  float Q = rq[0] + rq[1] + rq[2] + rq[3];
  float mean = S * (1.0f / DD);
  float var = Q * (1.0f / DD) - mean * mean;
  float rstd = rsqrtf(var + 1e-5f);
  float4 wv4 = ((const float4*)w)[tid];
  float4 bv4 = ((const float4*)b)[tid];
  float4 r;
  r.x = (v.x - mean) * rstd * wv4.x + bv4.x;
  r.y = (v.y - mean) * rstd * wv4.y + bv4.y;
  r.z = (v.z - mean) * rstd * wv4.z + bv4.z;
  r.w = (v.w - mean) * rstd * wv4.w + bv4.w;
  ((float4*)(out + (long long)row * DD))[tid] = r;
  if (yp) {
    float rr[4] = {r.x, r.y, r.z, r.w};
    short a0[4], a1[4], a2[4];
#pragma unroll
    for (int j = 0; j < 4; j++) split3(rr[j], a0[j], a1[j], a2[j]);
    size_t off = (size_t)row * DD + tid * 4;
    *(short4*)(yp + off)                    = make_short4(a0[0], a0[1], a0[2], a0[3]);
    *(short4*)(yp + (size_t)NN*DD + off)    = make_short4(a1[0], a1[1], a1[2], a1[3]);
    *(short4*)(yp + (size_t)2*NN*DD + off)  = make_short4(a2[0], a2[1], a2[2], a2[3]);
  }
}

// ---------------- fp32 tiled GEMM (fallback path) ----------------
__global__ __launch_bounds__(256) void gemm_kernel(
    const float* __restrict__ Aall, const float* __restrict__ Ball,
    const float* __restrict__ biasAll, const float* __restrict__ resAll,
    float* __restrict__ Call, int M, int Nn, int Kd, int flags,
    long long sA, long long sB, long long sBias, long long sC) {
  const float* A = Aall + (long long)blockIdx.z * sA;
  const float* B = Ball + (long long)blockIdx.z * sB;
  float* C = Call + (long long)blockIdx.z * sC;
  __shared__ float As[128 * 17];
  __shared__ float Bs[128 * 17];
  int tid = threadIdx.x;
  int tx = tid & 15, ty = tid >> 4;
  int bm = blockIdx.y * 128, bn = blockIdx.x * 128;
  int lrow = tid >> 2;
  int lk = (tid & 3) << 2;
  float acc[8][8];
#pragma unroll
  for (int i = 0; i < 8; i++)
#pragma unroll
    for (int j = 0; j < 8; j++) acc[i][j] = 0.f;
  const float* Arow0 = A + (long long)(bm + lrow) * Kd + lk;
  const float* Arow1 = A + (long long)(bm + lrow + 64) * Kd + lk;
  const float* Brow0 = B + (long long)(bn + lrow) * Kd + lk;
  const float* Brow1 = B + (long long)(bn + lrow + 64) * Kd + lk;
  for (int kb = 0; kb < Kd; kb += 16) {
    float4 a0 = *(const float4*)(Arow0 + kb);
    float4 a1 = *(const float4*)(Arow1 + kb);
    float4 b0 = *(const float4*)(Brow0 + kb);
    float4 b1 = *(const float4*)(Brow1 + kb);
    __syncthreads();
    As[lrow * 17 + lk + 0] = a0.x; As[lrow * 17 + lk + 1] = a0.y;
    As[lrow * 17 + lk + 2] = a0.z; As[lrow * 17 + lk + 3] = a0.w;
    As[(lrow + 64) * 17 + lk + 0] = a1.x; As[(lrow + 64) * 17 + lk + 1] = a1.y;
    As[(lrow + 64) * 17 + lk + 2] = a1.z; As[(lrow + 64) * 17 + lk + 3] = a1.w;
    Bs[lrow * 17 + lk + 0] = b0.x; Bs[lrow * 17 + lk + 1] = b0.y;
    Bs[lrow * 17 + lk + 2] = b0.z; Bs[lrow * 17 + lk + 3] = b0.w;
    Bs[(lrow + 64) * 17 + lk + 0] = b1.x; Bs[(lrow + 64) * 17 + lk + 1] = b1.y;
    Bs[(lrow + 64) * 17 + lk + 2] = b1.z; Bs[(lrow + 64) * 17 + lk + 3] = b1.w;
    __syncthreads();
#pragma unroll
    for (int k = 0; k < 16; k++) {
      float av[8], bv[8];
#pragma unroll
      for (int i = 0; i < 8; i++) av[i] = As[(ty + 16 * i) * 17 + k];
#pragma unroll
      for (int j = 0; j < 8; j++) bv[j] = Bs[(tx + 16 * j) * 17 + k];
#pragma unroll
      for (int i = 0; i < 8; i++)
#pragma unroll
        for (int j = 0; j < 8; j++) acc[i][j] = fmaf(av[i], bv[j], acc[i][j]);
    }
  }
  const float* bias = (flags & 1) ? (biasAll + (long long)blockIdx.z * sBias) : nullptr;
  const float* res = (flags & 4) ? (resAll + (long long)blockIdx.z * sC) : nullptr;
#pragma unroll
  for (int i = 0; i < 8; i++) {
    int row = bm + ty + 16 * i;
#pragma unroll
    for (int j = 0; j < 8; j++) {
      int col = bn + tx + 16 * j;
      float v = acc[i][j];
      if (flags & 1) v += bias[col];
      if (flags & 2) v = fmaxf(v, 0.f);
      if (flags & 4) v += res[(long long)row * Nn + col];
      C[(long long)row * Nn + col] = v;
    }
  }
}

// ---------------- bf16x3 emulated-fp32 MFMA GEMM (m97 structure) ----------------
// C = A(MxK) * B(NxK)^T from pre-split bf16 planes (Ap/Bp: [3][batch][rows][K]).
// flags: 1=bias, 2=relu, 4=residual(fp32 C only), 8=fast(3 products), 16=C as bf16x3 planes,
//        bits 8..15 = splitK.
__global__ __launch_bounds__(256, 3) void gemm_mfma(
    const short* __restrict__ Ap, const short* __restrict__ Bp,
    const float* __restrict__ biasAll, const float* __restrict__ resAll,
    void* __restrict__ Call, int M, int Nn, int Kd, int flags,
    long long sA, long long sB, long long sBias, long long sC,
    long long PA, long long PB, long long PC) {
  const bool fast = (flags & 8);
  const int np = fast ? 2 : 3;
  const int splitK = (flags >> 8) & 0xff;
  __shared__ short As[3][128][32];
  __shared__ short Bs[3][128][32];
  int tid = threadIdx.x;

  // ---- XCD-aware swizzle of flattened block index ----
  int gx = gridDim.x, gy = gridDim.y;
  int nwg = gx * gy * gridDim.z;
  int flat = blockIdx.x + gx * (blockIdx.y + gy * blockIdx.z);
  int cpx = nwg >> 3;
  int wkid = (flat & 7) * cpx + (flat >> 3);
  int bz = wkid / (gx * gy);
  int rem = wkid - bz * gx * gy;
  int by = rem / gx, bx = rem - by * gx;

  int sk = 0, e = bz, kLen = Kd;
  if (splitK > 1) { sk = bz % splitK; e = bz / splitK; kLen = Kd / splitK; }
  int k0 = sk * kLen;

  int bm = by * 128, bn = bx * 128;
  long long zA = (long long)e * sA;
  long long zB = (long long)e * sB;

  int wid = tid >> 6, lane = tid & 63;
  int lrow = lane >> 2, lchunk = lane & 3;
  int cs = lchunk ^ ((lrow >> 1) & 3);
  const short* gAbase = Ap + zA + (long long)(bm + wid * 16 + lrow) * Kd + cs * 8;
  const short* gBbase = Bp + zB + (long long)(bn + wid * 16 + lrow) * Kd + cs * 8;
  long long hstepA = (long long)64 * Kd;

  int wm = (wid & 1) * 64, wn = (wid >> 1) * 64;
  int tr = lane & 15, quad = lane >> 4;
  int qsw = (quad ^ ((tr >> 1) & 3)) << 3;

  f32x4 acc[4][4];
#pragma unroll
  for (int i = 0; i < 4; i++)
#pragma unroll
    for (int j = 0; j < 4; j++) acc[i][j] = (f32x4){0.f, 0.f, 0.f, 0.f};

  for (int kb = k0; kb < k0 + kLen; kb += 32) {
    __syncthreads();
#pragma unroll
    for (int p = 0; p < 3; p++) {
      if (p < np) {
#pragma unroll
        for (int h = 0; h < 2; h++) {
          int rb = h * 64 + wid * 16;
          gld16(gAbase + p * PA + h * hstepA + kb, &As[p][rb][0]);
          gld16(gBbase + p * PB + h * hstepA + kb, &Bs[p][rb][0]);
        }
      }
    }
    __syncthreads();
    bf16x8 af[4][3];
#pragma unroll
    for (int mi = 0; mi < 4; mi++) {
      int ar = wm + mi * 16 + tr;
      af[mi][0] = *(const bf16x8*)&As[0][ar][qsw];
      af[mi][1] = *(const bf16x8*)&As[1][ar][qsw];
      af[mi][2] = fast ? af[mi][0] : *(const bf16x8*)&As[2][ar][qsw];
    }
#pragma unroll
    for (int nj = 0; nj < 4; nj++) {
      int br = wn + nj * 16 + tr;
      bf16x8 b0 = *(const bf16x8*)&Bs[0][br][qsw];
      bf16x8 b1 = *(const bf16x8*)&Bs[1][br][qsw];
      bf16x8 b2 = fast ? b0 : *(const bf16x8*)&Bs[2][br][qsw];
#pragma unroll
      for (int mi = 0; mi < 4; mi++) {
        f32x4 c = acc[mi][nj];
        c = __builtin_amdgcn_mfma_f32_16x16x32_bf16(af[mi][1], b0, c, 0, 0, 0); // a1b0
        c = __builtin_amdgcn_mfma_f32_16x16x32_bf16(af[mi][0], b1, c, 0, 0, 0); // a0b1
        if (!fast) {
          c = __builtin_amdgcn_mfma_f32_16x16x32_bf16(af[mi][2], b0, c, 0, 0, 0); // a2b0
          c = __builtin_amdgcn_mfma_f32_16x16x32_bf16(af[mi][1], b1, c, 0, 0, 0); // a1b1
          c = __builtin_amdgcn_mfma_f32_16x16x32_bf16(af[mi][0], b2, c, 0, 0, 0); // a0b2
        }
        c = __builtin_amdgcn_mfma_f32_16x16x32_bf16(af[mi][0], b0, c, 0, 0, 0);   // a0b0
        acc[mi][nj] = c;
      }
    }
  }

  long long z = e;
  if (splitK > 1) {
    int NB = nwg / (gx * gy) / splitK;
    float* P = (float*)Call;
    long long base = ((long long)sk * NB + e) * sC;
#pragma unroll
    for (int mi = 0; mi < 4; mi++)
#pragma unroll
      for (int nj = 0; nj < 4; nj++) {
        int col = bn + wn + nj * 16 + tr;
#pragma unroll
        for (int rg = 0; rg < 4; rg++) {
          int row = bm + wm + mi * 16 + quad * 4 + rg;
          P[base + (long long)row * Nn + col] = acc[mi][nj][rg];
        }
      }
    return;
  }
  const float* bias = (flags & 1) ? (biasAll + z * sBias) : nullptr;
  if (flags & 16) {
    short* Cs = (short*)Call;
#pragma unroll
    for (int mi = 0; mi < 4; mi++)
#pragma unroll
      for (int nj = 0; nj < 4; nj++) {
        int col = bn + wn + nj * 16 + tr;
#pragma unroll
        for (int rg = 0; rg < 4; rg++) {
          int row = bm + wm + mi * 16 + quad * 4 + rg;
          float v = acc[mi][nj][rg];
          if (flags & 1) v += bias[col];
          if (flags & 2) v = fmaxf(v, 0.f);
          short s0, s1, s2;
          split3(v, s0, s1, s2);
          long long off = z * sC + (long long)row * Nn + col;
          Cs[off] = s0; Cs[PC + off] = s1; Cs[2 * PC + off] = s2;
        }
      }
  } else {
    float* C = (float*)Call;
    const float* res = (flags & 4) ? (resAll + z * sC) : nullptr;
#pragma unroll
    for (int mi = 0; mi < 4; mi++)
#pragma unroll
      for (int nj = 0; nj < 4; nj++) {
        int col = bn + wn + nj * 16 + tr;
#pragma unroll
        for (int rg = 0; rg < 4; rg++) {
          int row = bm + wm + mi * 16 + quad * 4 + rg;
          float v = acc[mi][nj][rg];
          if (flags & 1) v += bias[col];
          if (flags & 2) v = fmaxf(v, 0.f);
          if (flags & 4) v += res[(long long)row * Nn + col];
          C[z * sC + (long long)row * Nn + col] = v;
        }
      }
  }
  (void)M;
}

// ---------------- split-K reduce ----------------
__global__ __launch_bounds__(256) void reduce_kernel(
    float* __restrict__ dst, const float* __restrict__ part,
    const float* __restrict__ biasAll, int splits, long long total,
    int Nn, long long MNn, long long sBias, int flags) {
  long long i = ((long long)blockIdx.x * 256 + threadIdx.x) * 4;
  if (i >= total) return;
  float4 v = make_float4(0.f, 0.f, 0.f, 0.f);
  for (int s = 0; s < splits; s++) {
    float4 p = *(const float4*)(part + (long long)s * total + i);
    v.x += p.x; v.y += p.y; v.z += p.z; v.w += p.w;
  }
  if (flags & 1) {
    long long e = i / MNn;
    int col = (int)(i % Nn);
    const float* b = biasAll + e * sBias + col;
    v.x += b[0]; v.y += b[1]; v.z += b[2]; v.w += b[3];
  }
  if (flags & 4) {
    float4 r = *(const float4*)(dst + i);
    v.x += r.x; v.y += r.y; v.z += r.z; v.w += r.w;
  }
  *(float4*)(dst + i) = v;
}

// ---------------- RoPE in place (fallback path) ----------------
__global__ __launch_bounds__(256) void rope_kernel(float* __restrict__ qkv,
                                                   const float* __restrict__ st,
                                                   const float* __restrict__ ct) {
  int t = blockIdx.x, tid = threadIdx.x;
#pragma unroll
  for (int p = tid; p < HH * HALF; p += 256) {
    int h = p >> 5, i = p & 31;
    float s = st[t * HALF + i], c = ct[t * HALF + i];
    float* q = qkv + (long long)t * (3 * DD) + h * HSS;
    float q1 = q[i], q2 = q[i + HALF];
    q[i] = q1 * c - q2 * s;
    q[i + HALF] = q2 * c + q1 * s;
    float* k = q + DD;
    float k1 = k[i], k2 = k[i + HALF];
    k[i] = k1 * c - k2 * s;
    k[i + HALF] = k2 * c + k1 * s;
  }
}

// ---------------- RoPE + Q/K bf16x2-plane emit (mfma path) ----------------
// Qp/Kp layout: [(head*2 + plane)][t][64] bf16
__global__ __launch_bounds__(256) void qk_rope_planes_kernel(
    const float* __restrict__ qkv, const float* __restrict__ st, const float* __restrict__ ct,
    short* __restrict__ Qp, short* __restrict__ Kp) {
  int h = blockIdx.x >> 5, tb = blockIdx.x & 31;
  int tid = threadIdx.x;
  int d0 = (tid & 7) * 4;
#pragma unroll
  for (int pp = 0; pp < 2; pp++) {
    int t = tb * 64 + pp * 32 + (tid >> 3);
    const float* row = qkv + (size_t)t * (3 * DD) + h * HSS;
    float4 qa = *(const float4*)(row + d0);
    float4 qb = *(const float4*)(row + d0 + HALF);
    float4 ka = *(const float4*)(row + DD + d0);
    float4 kb = *(const float4*)(row + DD + d0 + HALF);
    float4 s4 = *(const float4*)(st + (size_t)t * HALF + d0);
    float4 c4 = *(const float4*)(ct + (size_t)t * HALF + d0);
    float qa_[4] = {qa.x, qa.y, qa.z, qa.w}, qb_[4] = {qb.x, qb.y, qb.z, qb.w};
    float ka_[4] = {ka.x, ka.y, ka.z, ka.w}, kb_[4] = {kb.x, kb.y, kb.z, kb.w};
    float ss[4] = {s4.x, s4.y, s4.z, s4.w}, cc[4] = {c4.x, c4.y, c4.z, c4.w};
    short qh0[4], ql0[4], qh1[4], ql1[4];
    short kh0[4], kl0[4], kh1[4], kl1[4];
#pragma unroll
    for (int u = 0; u < 4; u++) {
      float o1 = qa_[u] * cc[u] - qb_[u] * ss[u];
      float o2 = qb_[u] * cc[u] + qa_[u] * ss[u];
      split2(o1, qh0[u], ql0[u]);
      split2(o2, qh1[u], ql1[u]);
      float p1 = ka_[u] * cc[u] - kb_[u] * ss[u];
      float p2 = kb_[u] * cc[u] + ka_[u] * ss[u];
      split2(p1, kh0[u], kl0[u]);
      split2(p2, kh1[u], kl1[u]);
    }
    size_t b0 = ((size_t)(h * 2 + 0) * TT + t) * 64 + d0;
    size_t b1 = ((size_t)(h * 2 + 1) * TT + t) * 64 + d0;
    *(short4*)(Qp + b0)        = make_short4(qh0[0], qh0[1], qh0[2], qh0[3]);
    *(short4*)(Qp + b0 + HALF) = make_short4(qh1[0], qh1[1], qh1[2], qh1[3]);
    *(short4*)(Qp + b1)        = make_short4(ql0[0], ql0[1], ql0[2], ql0[3]);
    *(short4*)(Qp + b1 + HALF) = make_short4(ql1[0], ql1[1], ql1[2], ql1[3]);
    *(short4*)(Kp + b0)        = make_short4(kh0[0], kh0[1], kh0[2], kh0[3]);
    *(short4*)(Kp + b0 + HALF) = make_short4(kh1[0], kh1[1], kh1[2], kh1[3]);
    *(short4*)(Kp + b1)        = make_short4(kl0[0], kl0[1], kl0[2], kl0[3]);
    *(short4*)(Kp + b1 + HALF) = make_short4(kl1[0], kl1[1], kl1[2], kl1[3]);
  }
}

// ---------------- V bf16x2-plane transposed emit: Vt[(head*2+p)][d][t] ----------------
__global__ __launch_bounds__(256) void v_planes_kernel(const float* __restrict__ qkv,
                                                       short* __restrict__ Vt) {
  int h = blockIdx.x >> 5, tb = blockIdx.x & 31;
  int tid = threadIdx.x;
  __shared__ float Vsl[64][65];
#pragma unroll
  for (int pp = 0; pp < 4; pp++) {
    int r = pp * 16 + (tid >> 4);
    int d0 = (tid & 15) * 4;
    float4 v = *(const float4*)(qkv + (size_t)(tb * 64 + r) * (3 * DD) + 2 * DD + h * HSS + d0);
    Vsl[r][d0] = v.x; Vsl[r][d0 + 1] = v.y; Vsl[r][d0 + 2] = v.z; Vsl[r][d0 + 3] = v.w;
  }
  __syncthreads();
  int d = tid >> 2, tq = tid & 3;
  short hs[16], lsv[16];
#pragma unroll
  for (int jj = 0; jj < 16; jj++) split2(Vsl[tq * 16 + jj][d], hs[jj], lsv[jj]);
  size_t b0 = ((size_t)(h * 2 + 0) * 64 + d) * TT + tb * 64 + tq * 16;
  size_t b1 = ((size_t)(h * 2 + 1) * 64 + d) * TT + tb * 64 + tq * 16;
#pragma unroll
  for (int g = 0; g < 4; g++) {
    *(short4*)(Vt + b0 + g * 4) = make_short4(hs[g*4], hs[g*4+1], hs[g*4+2], hs[g*4+3]);
    *(short4*)(Vt + b1 + g * 4) = make_short4(lsv[g*4], lsv[g*4+1], lsv[g*4+2], lsv[g*4+3]);
  }
}

// ---------------- MFMA flash attention (bf16x2 emulated, causal) ----------------
// Block = (head, 64-row q-chunk); 4 waves x 16 q-rows. Swapped QK^T (S^T = K·Q^T) so
// each lane's softmax row is local+2 shfl_xor. K/V staged via global_load_lds with
// source-side XOR chunk swizzle (2-way free frag reads). P -> bf16x2 via wave-private
// LDS tile. O accumulated fp32 with online rescale. Output: attn planes only.
__global__ __launch_bounds__(256, 3) void attn_mfma_kernel(
    const short* __restrict__ Qp, const short* __restrict__ Kp,
    const short* __restrict__ Vt, short* __restrict__ ap) {
  int bid = blockIdx.x;
  int head = bid & 15;
  int qc = (bid < 256) ? (31 - (bid >> 4)) : ((bid - 256) >> 4);
  int tid = threadIdx.x;
  int w = tid >> 6, lane = tid & 63;
  int tr = lane & 15, quad = lane >> 4;
  int lr = lane >> 3, lc = lane & 7;

  __shared__ short Ks[2][64][64];
  __shared__ short Vs[2][64][64];
  __shared__ short Ps[4][2][16][64];

  // Q fragments in registers (B-operand: rows = q)
  bf16x8 qf[2][2];
  int qrow = qc * 64 + w * 16 + tr;
#pragma unroll
  for (int kk = 0; kk < 2; kk++)
#pragma unroll
    for (int p = 0; p < 2; p++)
      qf[kk][p] = *(const bf16x8*)(Qp + ((size_t)(head * 2 + p) * TT + qrow) * 64 + kk * 32 + quad * 8);

  f32x4 acc_o[4];
#pragma unroll
  for (int nj = 0; nj < 4; nj++) acc_o[nj] = (f32x4){0.f, 0.f, 0.f, 0.f};
  float m = -INFINITY, l = 0.f;

  int nkt = qc + 1;
  for (int kt = 0; kt < nkt; kt++) {
    __syncthreads();
#pragma unroll
    for (int p = 0; p < 2; p++)
#pragma unroll
      for (int h = 0; h < 2; h++) {
        int r = h * 32 + w * 8 + lr;
        gld16(Kp + ((size_t)(head * 2 + p) * TT + kt * 64 + r) * 64 + (lc ^ (r & 7)) * 8,
              &Ks[p][h * 32 + w * 8][0]);
        gld16(Vt + ((size_t)(head * 2 + p) * 64 + r) * TT + kt * 64 + (lc ^ (r & 7)) * 8,
              &Vs[p][h * 32 + w * 8][0]);
      }
    __syncthreads();

    // S^T = K·Q^T  (rows = keys, cols = q)
    f32x4 sc[4];
#pragma unroll
    for (int mi = 0; mi < 4; mi++) {
      f32x4 s = (f32x4){0.f, 0.f, 0.f, 0.f};
      int kr = mi * 16 + tr;
#pragma unroll
      for (int kk = 0; kk < 2; kk++) {
        int cidx = ((kk * 4 + quad) ^ (kr & 7)) * 8;
        bf16x8 k0 = *(const bf16x8*)&Ks[0][kr][cidx];
        bf16x8 k1 = *(const bf16x8*)&Ks[1][kr][cidx];
        s = __builtin_amdgcn_mfma_f32_16x16x32_bf16(k1, qf[kk][0], s, 0, 0, 0); // Kl·Qh
        s = __builtin_amdgcn_mfma_f32_16x16x32_bf16(k0, qf[kk][1], s, 0, 0, 0); // Kh·Ql
        s = __builtin_amdgcn_mfma_f32_16x16x32_bf16(k0, qf[kk][0], s, 0, 0, 0); // Kh·Qh
      }
      sc[mi] = s;
    }
    // scale + causal mask; lane holds keys {mi*16+quad*4+rg} for q = w*16+tr
    bool diag = (kt == qc);
    float pmax = -INFINITY;
#pragma unroll
    for (int mi = 0; mi < 4; mi++)
#pragma unroll
      for (int rg = 0; rg < 4; rg++) {
        float v = sc[mi][rg] * 0.125f;
        if (diag && (mi * 16 + quad * 4 + rg > w * 16 + tr)) v = -1e30f;
        sc[mi][rg] = v;
        pmax = fmaxf(pmax, v);
      }
    pmax = fmaxf(pmax, __shfl_xor(pmax, 16));
    pmax = fmaxf(pmax, __shfl_xor(pmax, 32));
    float mnew = fmaxf(m, pmax);
    float scl = __expf(m - mnew);
    m = mnew;
    float ps = 0.f;
#pragma unroll
    for (int mi = 0; mi < 4; mi++)
#pragma unroll
      for (int rg = 0; rg < 4; rg++) {
        float p = __expf(sc[mi][rg] - mnew);
        sc[mi][rg] = p;
        ps += p;
      }
    ps += __shfl_xor(ps, 16);
    ps += __shfl_xor(ps, 32);
    l = l * scl + ps;
    // P -> bf16x2 planes in wave-private LDS (8B-chunk swizzle matching 16B read swizzle)
#pragma unroll
    for (int mi = 0; mi < 4; mi++) {
      short h0, h1, h2, h3, l0, l1, l2, l3;
      split2(sc[mi][0], h0, l0); split2(sc[mi][1], h1, l1);
      split2(sc[mi][2], h2, l2); split2(sc[mi][3], h3, l3);
      int off8 = ((mi * 4 + quad) ^ ((tr & 7) << 1)) * 4;
      *(short4*)&Ps[w][0][tr][off8] = make_short4(h0, h1, h2, h3);
      *(short4*)&Ps[w][1][tr][off8] = make_short4(l0, l1, l2, l3);
    }
    asm volatile("s_waitcnt lgkmcnt(0)" ::: "memory");
    // rescale O (per output row q = quad*4+rg)
    float srg[4];
#pragma unroll
    for (int rg = 0; rg < 4; rg++) srg[rg] = __shfl(scl, quad * 4 + rg);
#pragma unroll
    for (int nj = 0; nj < 4; nj++)
#pragma unroll
      for (int rg = 0; rg < 4; rg++) acc_o[nj][rg] *= srg[rg];
    // PV: O += P · V^T
    bf16x8 pf[2][2];
#pragma unroll
    for (int ks = 0; ks < 2; ks++)
#pragma unroll
      for (int pl = 0; pl < 2; pl++)
        pf[ks][pl] = *(const bf16x8*)&Ps[w][pl][tr][((ks * 4 + quad) ^ (tr & 7)) * 8];
#pragma unroll
    for (int nj = 0; nj < 4; nj++) {
      f32x4 o = acc_o[nj];
      int vr = nj * 16 + tr;
#pragma unroll
      for (int ks = 0; ks < 2; ks++) {
        int cidx = ((ks * 4 + quad) ^ (vr & 7)) * 8;
        bf16x8 v0 = *(const bf16x8*)&Vs[0][vr][cidx];
        bf16x8 v1 = *(const bf16x8*)&Vs[1][vr][cidx];
        o = __builtin_amdgcn_mfma_f32_16x16x32_bf16(pf[ks][1], v0, o, 0, 0, 0); // Pl·Vh
        o = __builtin_amdgcn_mfma_f32_16x16x32_bf16(pf[ks][0], v1, o, 0, 0, 0); // Ph·Vl
        o = __builtin_amdgcn_mfma_f32_16x16x32_bf16(pf[ks][0], v0, o, 0, 0, 0); // Ph·Vh
      }
      acc_o[nj] = o;
    }
  }

  // epilogue: O /= l, emit bf16x3 planes in [head][t][d] flat order
  float rl[4];
#pragma unroll
  for (int rg = 0; rg < 4; rg++) rl[rg] = 1.f / __shfl(l, quad * 4 + rg);
#pragma unroll
  for (int nj = 0; nj < 4; nj++)
#pragma unroll
    for (int rg = 0; rg < 4; rg++) {
      float v = acc_o[nj][rg] * rl[rg];
      int q = qc * 64 + w * 16 + quad * 4 + rg;
      int d = nj * 16 + tr;
      size_t oaddr = (size_t)head * TT * HSS + (size_t)q * HSS + d;
      short s0, s1, s2;
      split3(v, s0, s1, s2);
      ap[oaddr] = s0;
      ap[(size_t)NN * DD + oaddr] = s1;
      ap[(size_t)2 * NN * DD + oaddr] = s2;
    }
}

// ---------------- flash attention (fp32 VALU, fallback path) ----------------
__global__ __launch_bounds__(256, 1) void attn_kernel(const float* __restrict__ qkv,
                                                      float* __restrict__ attn,
                                                      short* __restrict__ ap) {
  int bid = blockIdx.x;
  int head = bid & 15;
  int qc = (bid < 256) ? (31 - (bid >> 4)) : ((bid - 256) >> 4);
  int tid = threadIdx.x;
  int w = tid >> 6;
  int r = tid & 63;
  int qrow = qc * 64 + r;
  int nkt = qc + 1;

  __shared__ float4 KVbuf[4][2][16][16];
  __shared__ float Ms[4][64];
  __shared__ float Ls[4][64];

  float4 q[16], o[16];
  const float4* qp = (const float4*)(qkv + (long long)qrow * (3 * DD) + head * HSS);
#pragma unroll
  for (int d = 0; d < 16; d++) { q[d] = qp[d]; o[d] = make_float4(0.f, 0.f, 0.f, 0.f); }
  float m = -INFINITY, l = 0.f;

  for (int kt = w; kt < nkt; kt += 4) {
    bool diag = (kt == qc);
#pragma unroll 1
    for (int s = 0; s < 4; s++) {
      int kbase = kt * 64 + s * 16;
#pragma unroll
      for (int it = 0; it < 4; it++) {
        int fid = r + it * 64;
        int krow = fid >> 4, d4 = fid & 15;
        const float* bK = qkv + (long long)(kbase + krow) * (3 * DD) + DD + head * HSS + d4 * 4;
        KVbuf[w][0][krow][d4] = *(const float4*)bK;
        KVbuf[w][1][krow][d4] = *(const float4*)(bK + DD);
      }
      float sbuf[16];
#pragma unroll
      for (int jj = 0; jj < 16; jj++) {
        const float4* kr = KVbuf[w][0][jj];
        float sv = 0.f;
#pragma unroll
        for (int d = 0; d < 16; d++) {
          float4 kv = kr[d];
          sv = fmaf(q[d].x, kv.x, sv); sv = fmaf(q[d].y, kv.y, sv);
          sv = fmaf(q[d].z, kv.z, sv); sv = fmaf(q[d].w, kv.w, sv);
        }
        sv *= 0.125f;
        if (diag && (kbase + jj > qrow)) sv = -1e30f;
        sbuf[jj] = sv;
      }
      float gm = m;
#pragma unroll
      for (int jj = 0; jj < 16; jj++) gm = fmaxf(gm, sbuf[jj]);
      float scale = __expf(m - gm);
      m = gm;
      l *= scale;
#pragma unroll
      for (int d = 0; d < 16; d++) {
        o[d].x *= scale; o[d].y *= scale; o[d].z *= scale; o[d].w *= scale;
      }
#pragma unroll
      for (int jj = 0; jj < 16; jj++) {
        float p = __expf(sbuf[jj] - m);
        l += p;
        const float4* vr = KVbuf[w][1][jj];
#pragma unroll
        for (int d = 0; d < 16; d++) {
          float4 vv = vr[d];
          o[d].x = fmaf(p, vv.x, o[d].x); o[d].y = fmaf(p, vv.y, o[d].y);
          o[d].z = fmaf(p, vv.z, o[d].z); o[d].w = fmaf(p, vv.w, o[d].w);
        }
      }
    }
  }

  typedef float4 OscRow[64][5];
  OscRow* Osc = reinterpret_cast<OscRow*>(&KVbuf[0][0][0][0]);
  int rr = tid & 63, ii = tid >> 6;
  long long obase = (long long)head * TT * HSS + (long long)(qc * 64 + rr) * HSS;
#pragma unroll
  for (int c = 0; c < 4; c++) {
    __syncthreads();
    Osc[w][r][0] = o[c * 4 + 0];
    Osc[w][r][1] = o[c * 4 + 1];
    Osc[w][r][2] = o[c * 4 + 2];
    Osc[w][r][3] = o[c * 4 + 3];
    if (c == 0) { Ms[w][r] = m; Ls[w][r] = l; }
    __syncthreads();
    float m0 = Ms[0][rr], m1 = Ms[1][rr], m2 = Ms[2][rr], m3 = Ms[3][rr];
    float M = fmaxf(fmaxf(m0, m1), fmaxf(m2, m3));
    float s0 = __expf(m0 - M), s1 = __expf(m1 - M);
    float s2 = __expf(m2 - M), s3 = __expf(m3 - M);
    float L = s0 * Ls[0][rr] + s1 * Ls[1][rr] + s2 * Ls[2][rr] + s3 * Ls[3][rr];
    float rlq = 1.f / L;
    float4 a0 = Osc[0][rr][ii], a1 = Osc[1][rr][ii];
    float4 a2 = Osc[2][rr][ii], a3 = Osc[3][rr][ii];
    float4 res;
    res.x = (s0 * a0.x + s1 * a1.x + s2 * a2.x + s3 * a3.x) * rlq;
    res.y = (s0 * a0.y + s1 * a1.y + s2 * a2.y + s3 * a3.y) * rlq;
    res.z = (s0 * a0.z + s1 * a1.z + s2 * a2.z + s3 * a3.z) * rlq;
    res.w = (s0 * a0.w + s1 * a1.w + s2 * a2.w + s3 * a3.w) * rlq;
    long long oaddr = obase + c * 16 + ii * 4;
    *(float4*)(attn + oaddr) = res;
    if (ap) {
      float rv[4] = {res.x, res.y, res.z, res.w};
      short p0[4], p1[4], p2[4];
#pragma unroll
      for (int j = 0; j < 4; j++) split3(rv[j], p0[j], p1[j], p2[j]);
      *(short4*)(ap + oaddr)                    = make_short4(p0[0], p0[1], p0[2], p0[3]);
      *(short4*)(ap + (size_t)NN*DD + oaddr)    = make_short4(p1[0], p1[1], p1[2], p1[3]);
      *(short4*)(ap + (size_t)2*NN*DD + oaddr)  = make_short4(p2[0], p2[1], p2[2], p2[3]);
    }
  }
}

// ---------------- router ----------------
__global__ __launch_bounds__(64) void router_kernel(
    const float* __restrict__ y, const float* __restrict__ rw, const float* __restrict__ rb,
    const float* __restrict__ nw, const float* __restrict__ nb, const float* __restrict__ noise,
    int* __restrict__ slot_e, float* __restrict__ slot_g) {
  int n = blockIdx.x;
  int lane = threadIdx.x;
  double accr[EE], accn[EE];
#pragma unroll
  for (int e = 0; e < EE; e++) { accr[e] = 0.0; accn[e] = 0.0; }
  for (int j = 0; j < 16; j++) {
    float xv = y[(long long)n * DD + j * 64 + lane];
#pragma unroll
    for (int e = 0; e < EE; e++) {
      accr[e] += (double)xv * (double)rw[e * DD + j * 64 + lane];
      accn[e] += (double)xv * (double)nw[e * DD + j * 64 + lane];
    }
  }
#pragma unroll
  for (int e = 0; e < EE; e++) {
    for (int off = 32; off > 0; off >>= 1) {
      accr[e] += __shfl_down(accr[e], off);
      accn[e] += __shfl_down(accn[e], off);
    }
  }
  if (lane == 0) {
    float noisy[EE];
#pragma unroll
    for (int e = 0; e < EE; e++) {
      float lg = (float)accr[e] + rb[e];
      float nl = (float)accn[e] + nb[e];
      float sp = (nl > 0.f) ? (nl + log1pf(expf(-nl))) : log1pf(expf(nl));
      noisy[e] = lg + noise[n * EE + e] * sp;
    }
    int i0 = 0;
#pragma unroll
    for (int e = 1; e < EE; e++) if (noisy[e] > noisy[i0]) i0 = e;
    int i1 = -1;
#pragma unroll
    for (int e = 0; e < EE; e++) {
      if (e == i0) continue;
      if (i1 < 0 || noisy[e] > noisy[i1]) i1 = e;
    }
    float v0 = noisy[i0], v1 = noisy[i1];
    float e1 = __expf(v1 - v0);
    float inv = 1.f / (1.f + e1);
    slot_e[2 * n] = i0; slot_e[2 * n + 1] = i1;
    slot_g[2 * n] = inv; slot_g[2 * n + 1] = e1 * inv;
  }
}

// ---------------- deterministic rank scan ----------------
__global__ __launch_bounds__(256) void scan_kernel(const int* __restrict__ slot_e,
                                                   int* __restrict__ slot_pos) {
  __shared__ int cnt[256 * EE];
  int tid = threadIdx.x;
  int base = tid * 16;
  int c[EE];
#pragma unroll
  for (int e = 0; e < EE; e++) c[e] = 0;
  int loc[16];
  for (int i = 0; i < 16; i++) {
    int e = slot_e[base + i];
    loc[i] = e;
    c[e]++;
  }
#pragma unroll
  for (int e = 0; e < EE; e++) cnt[tid * EE + e] = c[e];
  __syncthreads();
  if (tid < EE) {
    int run = 0;
    for (int t2 = 0; t2 < 256; t2++) {
      int v = cnt[t2 * EE + tid];
      cnt[t2 * EE + tid] = run;
      run += v;
    }
  }
  __syncthreads();
  int run[EE];
#pragma unroll
  for (int e = 0; e < EE; e++) run[e] = cnt[tid * EE + e];
  for (int i = 0; i < 16; i++) {
    int e = loc[i];
    int r = run[e]++;
    slot_pos[base + i] = (r < CAPP) ? (e * CAPP + r) : -1;
  }
}

// ---------------- dispatch (fp32 fallback) ----------------
__global__ __launch_bounds__(256) void dispatch_kernel(const float* __restrict__ y,
                                                       const int* __restrict__ slot_pos,
                                                       float* __restrict__ disp) {
  int i = blockIdx.x;
  int pos = slot_pos[i];
  if (pos < 0) return;
  int tok = i >> 1;
  ((float4*)(disp + (long long)pos * DD))[threadIdx.x] =
      ((const float4*)(y + (long long)tok * DD))[threadIdx.x];
}

// ---------------- dispatch (bf16x3 planes) ----------------
__global__ __launch_bounds__(256) void dispatch_planes_kernel(const short* __restrict__ yp,
                                                              const int* __restrict__ slot_pos,
                                                              short* __restrict__ dp) {
  int i = blockIdx.x;
  int pos = slot_pos[i];
  if (pos < 0) return;
  int tok = i >> 1;
#pragma unroll
  for (int p = 0; p < 3; p++) {
    short4 v = ((const short4*)(yp + (size_t)p * NN * DD + (size_t)tok * DD))[threadIdx.x];
    ((short4*)(dp + (size_t)p * EE * CAPP * DD + (size_t)pos * DD))[threadIdx.x] = v;
  }
}

// ---------------- combine ----------------
__global__ __launch_bounds__(256) void combine_kernel(float* __restrict__ x,
                                                      const float* __restrict__ eo,
                                                      const int* __restrict__ slot_pos,
                                                      const float* __restrict__ slot_g) {
  int n = blockIdx.x, tid = threadIdx.x;
  int p0 = slot_pos[2 * n], p1 = slot_pos[2 * n + 1];
  float g0 = slot_g[2 * n], g1 = slot_g[2 * n + 1];
  float4 v = ((float4*)(x + (long long)n * DD))[tid];
  if (p0 >= 0) {
    float4 e0 = ((const float4*)(eo + (long long)p0 * DD))[tid];
    v.x = fmaf(g0, e0.x, v.x); v.y = fmaf(g0, e0.y, v.y);
    v.z = fmaf(g0, e0.z, v.z); v.w = fmaf(g0, e0.w, v.w);
  }
  if (p1 >= 0) {
    float4 e1 = ((const float4*)(eo + (long long)p1 * DD))[tid];
    v.x = fmaf(g1, e1.x, v.x); v.y = fmaf(g1, e1.y, v.y);
    v.z = fmaf(g1, e1.z, v.z); v.w = fmaf(g1, e1.w, v.w);
  }
  ((float4*)(x + (long long)n * DD))[tid] = v;
}

extern "C" void kernel_launch(void* const* d_in, const int* in_sizes, int n_in,
                              void* d_out, int out_size, void* d_ws, size_t ws_size,
                              hipStream_t stream) {
  const int* input_ids = (const int*)d_in[0];
  const float* noise = (const float*)d_in[1];
  const float* tok_emb = (const float*)d_in[2];
  const float* pos_emb = (const float*)d_in[3];
  const float* ln1_w = (const float*)d_in[4];
  const float* ln1_b = (const float*)d_in[5];
  const float* ln2_w = (const float*)d_in[6];
  const float* ln2_b = (const float*)d_in[7];
  const float* qkv_w = (const float*)d_in[8];
  const float* out_w = (const float*)d_in[9];
  const float* router_w = (const float*)d_in[10];
  const float* router_b = (const float*)d_in[11];
  const float* noise_w = (const float*)d_in[12];
  const float* noise_b = (const float*)d_in[13];
  const float* e_w1 = (const float*)d_in[14];
  const float* e_b1 = (const float*)d_in[15];
  const float* e_w2 = (const float*)d_in[16];
  const float* e_b2 = (const float*)d_in[17];
  const float* lnf_w = (const float*)d_in[18];
  const float* lnf_b = (const float*)d_in[19];
  float* out = (float*)d_out;

  // ---- workspace layout ----
  float* ws = (float*)d_ws;
  size_t off = 0;
  float* x = ws + off;       off += (size_t)NN * DD;
  float* y = ws + off;       off += (size_t)NN * DD;
  float* qkv = ws + off;     off += (size_t)NN * 3 * DD;
  float* eo = ws + off;      off += (size_t)EE * CAPP * DD;
  float* sintab = ws + off;  off += (size_t)TT * HALF;
  float* costab = ws + off;  off += (size_t)TT * HALF;
  float* attn32 = ws + off;  off += (size_t)NN * DD;
  int* slot_e = (int*)(ws + off);   off += NK;
  int* slot_pos = (int*)(ws + off); off += NK;
  float* slot_g = ws + off;  off += NK;
  size_t base_floats = off;
  float* disp32 = ws + off;
  float* hbuf32 = disp32 + (size_t)EE * CAPP * DD;
  size_t fb_need = (base_floats + (size_t)EE * CAPP * DD + (size_t)EE * CAPP * DFF) * 4;

  short* sp = (short*)(ws + base_floats);
  short* y_p = sp;                                   sp += (size_t)3 * NN * DD;
  short* attn_p = sp;                                sp += (size_t)3 * NN * DD;
  short* disp_p = sp;                                sp += (size_t)3 * EE * CAPP * DD;
  short* hbuf_p = sp;                                sp += (size_t)3 * EE * CAPP * DFF;
  short* qkvw_p = sp;                                sp += (size_t)3 * LL * 3 * DD * DD;
  short* outw_p = sp;                                sp += (size_t)3 * LL * DD * DD;
  short* ew_p = sp;                                  sp += (size_t)3 * EE * DFF * DD;
  size_t mfma_need = (size_t)((char*)sp - (char*)d_ws);
  bool use_mfma = (ws_size >= mfma_need);
  (void)fb_need;

  // time-disjoint overlays inside hbuf_p (100.7 MB):
  //  - pQKV: QKV split-K partials (2 x NN x 3DD fp32 = 50.3 MB)   [before attn prep]
  //  - attn planes Qp/Kp/Vt (3 x 8.4 MB = 25.2 MB)                [attn prep/attn]
  //  - pAO: attn-out split-K partials (4 x NN x DD = 33.5 MB)     [after attn]
  //  - MoE-GEMM1 bf16x3 output planes (full region)               [after out-proj]
  float* pQKV = (float*)hbuf_p;
  float* pAO  = (float*)hbuf_p;
  float* pM2  = y;  // MoE-GEMM2 partials: y..qkv contiguous (4 x NN x DD fp32)
  short* attnQp = hbuf_p;
  short* attnKp = attnQp + (size_t)HH * 2 * TT * HSS;
  short* attnVt = attnKp + (size_t)HH * 2 * TT * HSS;

  embed_kernel<<<TT, 256, 0, stream>>>(input_ids, tok_emb, pos_emb, x);
  sincos_kernel<<<(TT * HALF) / 256, 256, 0, stream>>>(sintab, costab);

  if (use_mfma) {
    long long nq = (long long)LL * 3 * DD * DD;
    long long no = (long long)LL * DD * DD;
    convert_kernel<<<(int)(nq / 2048), 256, 0, stream>>>(qkv_w, qkvw_p, nq);
    convert_kernel<<<(int)(no / 2048), 256, 0, stream>>>(out_w, outw_p, no);
    long long ne = (long long)EE * DFF * DD;

    for (int l = 0; l < LL; l++) {
      int fastf = (l == LL - 1) ? 8 : 0;
      ln_kernel<<<NN, 256, 0, stream>>>(x, y, y_p, ln1_w + l * DD, ln1_b + l * DD);
      // QKV: split-K=2 -> 768 blocks; raw partials into hbuf_p
      gemm_mfma<<<dim3(3 * DD / 128, NN / 128, 2), 256, 0, stream>>>(
          y_p, qkvw_p + (size_t)l * 3 * DD * DD, nullptr, nullptr, pQKV,
          NN, 3 * DD, DD, (2 << 8), 0, 0, 0, (long long)NN * 3 * DD,
          (long long)NN * DD, (long long)LL * 3 * DD * DD, 0);
      reduce_kernel<<<(int)((long long)NN * 3 * DD / 1024), 256, 0, stream>>>(
          qkv, pQKV, nullptr, 2, (long long)NN * 3 * DD, 3 * DD,
          (long long)NN * 3 * DD, 0, 0);
      // RoPE fused into plane prep; V transposed planes
      qk_rope_planes_kernel<<<512, 256, 0, stream>>>(qkv, sintab, costab, attnQp, attnKp);
      v_planes_kernel<<<512, 256, 0, stream>>>(qkv, attnVt);
      attn_mfma_kernel<<<512, 256, 0, stream>>>(attnQp, attnKp, attnVt, attn_p);
      // attn-out: split-K=4 -> 512 blocks; residual applied in reduce
      gemm_mfma<<<dim3(DD / 128, NN / 128, 4), 256, 0, stream>>>(
          attn_p, outw_p + (size_t)l * DD * DD, nullptr, nullptr, pAO,
          NN, DD, DD, (4 << 8), 0, 0, 0, (long long)NN * DD,
          (long long)NN * DD, (long long)LL * DD * DD, 0);
      reduce_kernel<<<(int)((long long)NN * DD / 1024), 256, 0, stream>>>(
          x, pAO, nullptr, 4, (long long)NN * DD, DD, (long long)NN * DD, 0, 4);
      ln_kernel<<<NN, 256, 0, stream>>>(x, y, y_p, ln2_w + l * DD, ln2_b + l * DD);
      router_kernel<<<NN, 64, 0, stream>>>(
          y, router_w + (size_t)l * EE * DD, router_b + l * EE,
          noise_w + (size_t)l * EE * DD, noise_b + l * EE,
          noise + (size_t)l * NN * EE, slot_e, slot_g);
      scan_kernel<<<1, 256, 0, stream>>>(slot_e, slot_pos);
      dispatch_planes_kernel<<<NK, 256, 0, stream>>>(y_p, slot_pos, disp_p);
      convert_kernel<<<(int)(ne / 2048), 256, 0, stream>>>(e_w1 + (size_t)l * ne, ew_p, ne);
      gemm_mfma<<<dim3(DFF / 128, CAPP / 128, EE), 256, 0, stream>>>(
          disp_p, ew_p, e_b1 + (size_t)l * EE * DFF, nullptr, hbuf_p,
          CAPP, DFF, DD, 1 | 2 | 16 | fastf,
          (long long)CAPP * DD, (long long)DFF * DD, DFF, (long long)CAPP * DFF,
          (long long)EE * CAPP * DD, (long long)EE * DFF * DD, (long long)EE * CAPP * DFF);
      convert_kernel<<<(int)(ne / 2048), 256, 0, stream>>>(e_w2 + (size_t)l * ne, ew_p, ne);
      // MoE-GEMM2: split-K=2 -> 512 blocks; partials in y..qkv; bias in reduce
      gemm_mfma<<<dim3(DD / 128, CAPP / 128, EE * 2), 256, 0, stream>>>(
          hbuf_p, ew_p, nullptr, nullptr, pM2,
          CAPP, DD, DFF, fastf | (2 << 8),
          (long long)CAPP * DFF, (long long)DD * DFF, 0, (long long)CAPP * DD,
          (long long)EE * CAPP * DFF, (long long)EE * DD * DFF, 0);
      reduce_kernel<<<(int)((long long)EE * CAPP * DD / 1024), 256, 0, stream>>>(
          eo, pM2, e_b2 + (size_t)l * EE * DD, 2, (long long)EE * CAPP * DD, DD,
          (long long)CAPP * DD, DD, 1);
      combine_kernel<<<NN, 256, 0, stream>>>(x, eo, slot_pos, slot_g);
    }
  } else {
    for (int l = 0; l < LL; l++) {
      ln_kernel<<<NN, 256, 0, stream>>>(x, y, nullptr, ln1_w + l * DD, ln1_b + l * DD);
      gemm_kernel<<<dim3(3 * DD / 128, NN / 128, 1), 256, 0, stream>>>(
          y, qkv_w + (size_t)l * 3 * DD * DD, nullptr, nullptr, qkv,
          NN, 3 * DD, DD, 0, 0, 0, 0, 0);
      rope_kernel<<<TT, 256, 0, stream>>>(qkv, sintab, costab);
      attn_kernel<<<512, 256, 0, stream>>>(qkv, attn32, nullptr);
      gemm_kernel<<<dim3(DD / 128, NN / 128, 1), 256, 0, stream>>>(
          attn32, out_w + (size_t)l * DD * DD, nullptr, x, x,
          NN, DD, DD, 4, 0, 0, 0, 0);
      ln_kernel<<<NN, 256, 0, stream>>>(x, y, nullptr, ln2_w + l * DD, ln2_b + l * DD);
      router_kernel<<<NN, 64, 0, stream>>>(
          y, router_w + (size_t)l * EE * DD, router_b + l * EE,
          noise_w + (size_t)l * EE * DD, noise_b + l * EE,
          noise + (size_t)l * NN * EE, slot_e, slot_g);
      scan_kernel<<<1, 256, 0, stream>>>(slot_e, slot_pos);
      dispatch_kernel<<<NK, 256, 0, stream>>>(y, slot_pos, disp32);
      gemm_kernel<<<dim3(DFF / 128, CAPP / 128, EE), 256, 0, stream>>>(
          disp32, e_w1 + (size_t)l * EE * DFF * DD, e_b1 + (size_t)l * EE * DFF, nullptr, hbuf32,
          CAPP, DFF, DD, 3,
          (long long)CAPP * DD, (long long)DFF * DD, DFF, (long long)CAPP * DFF);
      gemm_kernel<<<dim3(DD / 128, CAPP / 128, EE), 256, 0, stream>>>(
          hbuf32, e_w2 + (size_t)l * EE * DD * DFF, e_b2 + (size_t)l * EE * DD, nullptr, eo,
          CAPP, DD, DFF, 1,
          (long long)CAPP * DFF, (long long)DD * DFF, DD, (long long)CAPP * DD);
      combine_kernel<<<NN, 256, 0, stream>>>(x, eo, slot_pos, slot_g);
    }
  }
  ln_kernel<<<NN, 256, 0, stream>>>(x, out, nullptr, lnf_w, lnf_b);
  (void)in_sizes; (void)n_in; (void)out_size; (void)ws_size;
}